// Round 6
// baseline (307.619 us; speedup 1.0000x reference)
//
#include <hip/hip_runtime.h>
#include <hip/hip_bf16.h>
#include <hip/hip_fp16.h>

static inline int cdiv(long long a, int b) { return (int)((a + b - 1) / b); }

#define LEAK 0.1f
__device__ __forceinline__ float leaky(float v) { return v >= 0.0f ? v : LEAK * v; }

// packed edge: bits[31:15] = src (17b), bits[14:0] = fp16(w) >> 1
__device__ __forceinline__ int dec_s(unsigned p) { return (int)(p >> 15); }
__device__ __forceinline__ float dec_w(unsigned p) {
    return __half2float(__ushort_as_half((unsigned short)((p & 0x7FFFu) << 1)));
}
__device__ __forceinline__ unsigned enc_sw(int s, float w) {
    return ((unsigned)s << 15) | ((unsigned)__half_as_ushort(__float2half_rn(w)) >> 1);
}

constexpr int BT = 256;        // threads per block (all build kernels)
constexpr int NBLK = 512;      // edge-partition blocks (phases A/C)
constexpr int CHUNK = 4096;    // edges staged in LDS per pass (phase C)
constexpr int BINS_MAX = 512;  // >= (N+255)/256 for N=100k (391)

// ---------------- phase A: per-(bin, block) histogram of dst>>8 ----------------
__global__ __launch_bounds__(BT) void k_hist(const int* __restrict__ dst, int* __restrict__ hist,
                                             int E, int EPB, int nbins) {
    __shared__ int h[BINS_MAX];
    for (int i = threadIdx.x; i < nbins; i += BT) h[i] = 0;
    __syncthreads();
    int base = blockIdx.x * EPB;
    int end = min(base + EPB, E);
    for (int i = base + threadIdx.x; i < end; i += BT) atomicAdd(&h[dst[i] >> 8], 1);
    __syncthreads();
    for (int i = threadIdx.x; i < nbins; i += BT) hist[(size_t)i * NBLK + blockIdx.x] = h[i];
}

// ---------------- phase B1: exclusive scan of each bin's row over blocks ----------------
__global__ __launch_bounds__(BT) void k_scan_cols(int* __restrict__ hist, int* __restrict__ binTot) {
    __shared__ int a[NBLK], b_[NBLK];
    int t = threadIdx.x;
    int* H = hist + (size_t)blockIdx.x * NBLK;
    for (int i = t; i < NBLK; i += BT) a[i] = H[i];
    __syncthreads();
    int* cur = a; int* nxt = b_;
    for (int off = 1; off < NBLK; off <<= 1) {
        for (int i = t; i < NBLK; i += BT) nxt[i] = cur[i] + (i >= off ? cur[i - off] : 0);
        __syncthreads();
        int* tm = cur; cur = nxt; nxt = tm;
    }
    for (int i = t; i < NBLK; i += BT) H[i] = (i ? cur[i - 1] : 0);
    if (t == 0) binTot[blockIdx.x] = cur[NBLK - 1];
}

// ---------------- phase B2: exclusive scan over bins ----------------
__global__ __launch_bounds__(BT) void k_scan_bins(const int* __restrict__ binTot,
                                                  int* __restrict__ binBase, int nbins) {
    __shared__ int a[BINS_MAX], b_[BINS_MAX];
    int t = threadIdx.x;
    for (int i = t; i < BINS_MAX; i += BT) a[i] = (i < nbins) ? binTot[i] : 0;
    __syncthreads();
    int* cur = a; int* nxt = b_;
    for (int off = 1; off < BINS_MAX; off <<= 1) {
        for (int i = t; i < BINS_MAX; i += BT) nxt[i] = cur[i] + (i >= off ? cur[i - off] : 0);
        __syncthreads();
        int* tm = cur; cur = nxt; nxt = tm;
    }
    for (int i = t; i < nbins; i += BT) binBase[i] = (i ? cur[i - 1] : 0);
    if (t == 0) binBase[nbins] = cur[nbins - 1];  // == E
}

// ---------------- phase C: LDS-staged scatter of edges into bin order ----------------
__global__ __launch_bounds__(BT) void k_scatter_bins(
    const int* __restrict__ src, const int* __restrict__ dst, const float* __restrict__ ew,
    const int* __restrict__ colOff, const int* __restrict__ binBase,
    unsigned* __restrict__ sortedP, unsigned char* __restrict__ sortedDlo,
    int E, int EPB, int nbins) {
    constexpr int EPT = CHUNK / BT;  // 16 edges per thread per chunk
    __shared__ unsigned sP[CHUNK];        // 16 KB
    __shared__ unsigned char sD[CHUNK];   // 4 KB
    __shared__ unsigned short sB[CHUNK];  // 8 KB
    __shared__ int h[BINS_MAX], sc[BINS_MAX], sc2[BINS_MAX];
    __shared__ int blkOff[BINS_MAX], cursor[BINS_MAX];

    int t = threadIdx.x, blk = blockIdx.x;
    for (int i = t; i < nbins; i += BT) {
        blkOff[i] = binBase[i] + colOff[(size_t)i * NBLK + blk];
        cursor[i] = 0;
    }
    int base = blk * EPB;
    int bend = min(base + EPB, E);
    for (int cb = base; cb < bend; cb += CHUNK) {
        int cnt = min(CHUNK, bend - cb);
        for (int i = t; i < nbins; i += BT) h[i] = 0;
        __syncthreads();
        int myBin[EPT], myRank[EPT], myD[EPT];
        unsigned myP[EPT];
#pragma unroll
        for (int k = 0; k < EPT; k++) {
            int li = k * BT + t;
            if (li < cnt) {
                int i = cb + li;
                int d = dst[i];
                myP[k] = enc_sw(src[i], ew[i]);
                myD[k] = d & 255;
                int b = d >> 8;
                myBin[k] = b;
                myRank[k] = atomicAdd(&h[b], 1);
            } else myBin[k] = -1;
        }
        __syncthreads();
        for (int i = t; i < BINS_MAX; i += BT) sc[i] = (i < nbins) ? h[i] : 0;
        __syncthreads();
        int* cur = sc; int* nxt = sc2;
        for (int off = 1; off < BINS_MAX; off <<= 1) {
            for (int i = t; i < BINS_MAX; i += BT) nxt[i] = cur[i] + (i >= off ? cur[i - off] : 0);
            __syncthreads();
            int* tm = cur; cur = nxt; nxt = tm;
        }
#pragma unroll
        for (int k = 0; k < EPT; k++) {
            int b = myBin[k];
            if (b >= 0) {
                int pos = (b ? cur[b - 1] : 0) + myRank[k];
                sP[pos] = myP[k];
                sD[pos] = (unsigned char)myD[k];
                sB[pos] = (unsigned short)b;
            }
        }
        __syncthreads();
        for (int i = t; i < cnt; i += BT) {
            int b = sB[i];
            int excl = (b ? cur[b - 1] : 0);
            int g = blkOff[b] + cursor[b] + (i - excl);
            sortedP[g] = sP[i];
            sortedDlo[g] = sD[i];
        }
        __syncthreads();
        for (int i = t; i < nbins; i += BT) cursor[i] += h[i];
        __syncthreads();
    }
}

// ---------------- phase D: per-bin counting sort -> CSR, plus node stats ----------------
// Computes weighted degree (LDS f32 atomics), writes dinv and x~0 = dinv * xin (fp16).
__global__ __launch_bounds__(BT) void k_bin_sort(
    const unsigned* __restrict__ sortedP, const unsigned char* __restrict__ sortedDlo,
    const int* __restrict__ binBase, const float* __restrict__ xin,
    unsigned* __restrict__ pairs, int* __restrict__ rowptr,
    float* __restrict__ dinv, __half2* __restrict__ x0h, int N, int E) {
    __shared__ int cnt[256], a[256], b_[256], cursor[256];
    __shared__ float degs[256];
    int bin = blockIdx.x, t = threadIdx.x;  // BT == 256
    int e0 = binBase[bin], e1 = binBase[bin + 1];
    int nodeBase = bin << 8;
    int nn = min(256, N - nodeBase);
    cnt[t] = 0;
    degs[t] = 0.0f;
    __syncthreads();
    for (int i = e0 + t; i < e1; i += BT) atomicAdd(&cnt[sortedDlo[i]], 1);
    __syncthreads();
    a[t] = cnt[t];
    __syncthreads();
    int* cur = a; int* nxt = b_;
    for (int off = 1; off < 256; off <<= 1) {
        nxt[t] = cur[t] + (t >= off ? cur[t - off] : 0);
        __syncthreads();
        int* tm = cur; cur = nxt; nxt = tm;
    }
    int ex = (t ? cur[t - 1] : 0);
    if (t < nn) rowptr[nodeBase + t] = e0 + ex;
    __syncthreads();
    cnt[t] = ex;   // repurpose: exclusive offset per local node
    cursor[t] = 0;
    __syncthreads();
    for (int i = e0 + t; i < e1; i += BT) {
        int dl = sortedDlo[i];
        unsigned v = sortedP[i];
        atomicAdd(&degs[dl], dec_w(v));
        int r = atomicAdd(&cursor[dl], 1);
        pairs[e0 + cnt[dl] + r] = v;
    }
    __syncthreads();
    if (t < nn) {
        int node = nodeBase + t;
        float d = 1.0f + degs[t];
        float di = rsqrtf(d);
        dinv[node] = di;
        float4 xv = *reinterpret_cast<const float4*>(xin + (size_t)node * 4);
        x0h[(size_t)node * 2 + 0] = __floats2half2_rn(xv.x * di, xv.y * di);
        x0h[(size_t)node * 2 + 1] = __floats2half2_rn(xv.z * di, xv.w * di);
    }
    if (bin == 0 && t == 0) rowptr[N] = E;
}

// ---------------- fused layer (layers 1,2) ----------------
// x~ fp16 rows (H = FIN/2 half2); out x~' = dinv*leaky((dv*(sum w x~ + x~self)) @ W + b)
// Output split across outA (first SPLITH half2) / outB (rest) so next layer's
// gather working sets are separate, L2-resident buffers.
template <int FIN, int FOUT, int SPLITH, int TPN>
__global__ void k_layer(const int* __restrict__ rowptr, const unsigned* __restrict__ pairs,
                        const __half2* __restrict__ x, const float* __restrict__ dinv,
                        const float* __restrict__ W, const float* __restrict__ b,
                        __half2* __restrict__ outA, __half2* __restrict__ outB, int N) {
    constexpr int H = FIN / 2;
    constexpr int H2O = FOUT / 2;
    constexpr int P = FOUT + 1;  // padded LDS row (bank-conflict fix)
    constexpr int KX = (H + TPN - 1) / TPN;
    constexpr int QX = (H2O + TPN - 1) / TPN;
    __shared__ float Ws[FIN * P];
    __shared__ float bs[FOUT];
    for (int t = threadIdx.x; t < FIN * FOUT; t += blockDim.x) {
        int r = t / FOUT, c = t - r * FOUT;
        Ws[r * P + c] = W[t];
    }
    for (int t = threadIdx.x; t < FOUT; t += blockDim.x) bs[t] = b[t];
    __syncthreads();
    int gid = blockIdx.x * blockDim.x + threadIdx.x;
    int node = gid / TPN;
    int l = gid & (TPN - 1);
    if (node >= N) return;
    int beg = rowptr[node], end = rowptr[node + 1];

    float2 acc[KX];
#pragma unroll
    for (int k = 0; k < KX; k++) acc[k] = make_float2(0.0f, 0.0f);

    int e = beg;
    for (; e + 4 <= end; e += 4) {
        unsigned q0 = pairs[e + 0], q1 = pairs[e + 1], q2 = pairs[e + 2], q3 = pairs[e + 3];
        const __half2* r0 = x + (size_t)dec_s(q0) * H;
        const __half2* r1 = x + (size_t)dec_s(q1) * H;
        const __half2* r2 = x + (size_t)dec_s(q2) * H;
        const __half2* r3 = x + (size_t)dec_s(q3) * H;
        float w0 = dec_w(q0), w1 = dec_w(q1), w2 = dec_w(q2), w3 = dec_w(q3);
#pragma unroll
        for (int k = 0; k < KX; k++) {
            int m = l + TPN * k;
            if (m < H) {
                float2 v0 = __half22float2(r0[m]);
                float2 v1 = __half22float2(r1[m]);
                float2 v2 = __half22float2(r2[m]);
                float2 v3 = __half22float2(r3[m]);
                acc[k].x += v0.x * w0 + v1.x * w1 + v2.x * w2 + v3.x * w3;
                acc[k].y += v0.y * w0 + v1.y * w1 + v2.y * w2 + v3.y * w3;
            }
        }
    }
    for (; e < end; e++) {
        unsigned q = pairs[e];
        const __half2* r = x + (size_t)dec_s(q) * H;
        float w = dec_w(q);
#pragma unroll
        for (int k = 0; k < KX; k++) {
            int m = l + TPN * k;
            if (m < H) {
                float2 v = __half22float2(r[m]);
                acc[k].x += v.x * w;
                acc[k].y += v.y * w;
            }
        }
    }
    {   // self-loop (weight 1)
        const __half2* rn = x + (size_t)node * H;
#pragma unroll
        for (int k = 0; k < KX; k++) {
            int m = l + TPN * k;
            if (m < H) {
                float2 v = __half22float2(rn[m]);
                acc[k].x += v.x;
                acc[k].y += v.y;
            }
        }
    }
    float dv = dinv[node];
    float p[FOUT];
#pragma unroll
    for (int j = 0; j < FOUT; j++) p[j] = 0.0f;
#pragma unroll
    for (int k = 0; k < KX; k++) {
        int m = l + TPN * k;
        if (m < H) {
            float ax = acc[k].x * dv;
            float ay = acc[k].y * dv;
            const float* w0r = Ws + (2 * m) * P;
            const float* w1r = Ws + (2 * m + 1) * P;
#pragma unroll
            for (int j = 0; j < FOUT; j++) p[j] += ax * w0r[j] + ay * w1r[j];
        }
    }
#pragma unroll
    for (int j = 0; j < FOUT; j++) {
        p[j] += __shfl_xor(p[j], 1);
        if constexpr (TPN == 4) p[j] += __shfl_xor(p[j], 2);
    }
#pragma unroll
    for (int q = 0; q < QX; q++) {
        int m = l + TPN * q;
        if (m < H2O) {
            float a0 = leaky(p[2 * m] + bs[2 * m]) * dv;
            float a1 = leaky(p[2 * m + 1] + bs[2 * m + 1]) * dv;
            __half2 hv = __floats2half2_rn(a0, a1);
            if (m < SPLITH) outA[(size_t)node * SPLITH + m] = hv;
            else outB[(size_t)node * (H2O - SPLITH) + (m - SPLITH)] = hv;
        }
    }
}

// ---------------- layer-3 pass 1: aggregate features 0-11 from h2a ----------------
// y[node][0:12] = sum_e w_e * x~a[src] + x~a[node]   (fp32, dinv applied later)
__global__ void k_agg(const int* __restrict__ rowptr, const unsigned* __restrict__ pairs,
                      const __half2* __restrict__ xa, float2* __restrict__ y2, int N) {
    constexpr int H = 6;
    int gid = blockIdx.x * blockDim.x + threadIdx.x;
    int node = gid >> 2;
    int l = gid & 3;
    if (node >= N) return;
    int beg = rowptr[node], end = rowptr[node + 1];
    float2 acc[2];
    acc[0] = make_float2(0.0f, 0.0f);
    acc[1] = make_float2(0.0f, 0.0f);
    int e = beg;
    for (; e + 4 <= end; e += 4) {
        unsigned q0 = pairs[e + 0], q1 = pairs[e + 1], q2 = pairs[e + 2], q3 = pairs[e + 3];
        const __half2* r0 = xa + (size_t)dec_s(q0) * H;
        const __half2* r1 = xa + (size_t)dec_s(q1) * H;
        const __half2* r2 = xa + (size_t)dec_s(q2) * H;
        const __half2* r3 = xa + (size_t)dec_s(q3) * H;
        float w0 = dec_w(q0), w1 = dec_w(q1), w2 = dec_w(q2), w3 = dec_w(q3);
#pragma unroll
        for (int k = 0; k < 2; k++) {
            int m = l + 4 * k;
            if (m < H) {
                float2 v0 = __half22float2(r0[m]);
                float2 v1 = __half22float2(r1[m]);
                float2 v2 = __half22float2(r2[m]);
                float2 v3 = __half22float2(r3[m]);
                acc[k].x += v0.x * w0 + v1.x * w1 + v2.x * w2 + v3.x * w3;
                acc[k].y += v0.y * w0 + v1.y * w1 + v2.y * w2 + v3.y * w3;
            }
        }
    }
    for (; e < end; e++) {
        unsigned q = pairs[e];
        const __half2* r = xa + (size_t)dec_s(q) * H;
        float w = dec_w(q);
#pragma unroll
        for (int k = 0; k < 2; k++) {
            int m = l + 4 * k;
            if (m < H) {
                float2 v = __half22float2(r[m]);
                acc[k].x += v.x * w;
                acc[k].y += v.y * w;
            }
        }
    }
    const __half2* rn = xa + (size_t)node * H;
#pragma unroll
    for (int k = 0; k < 2; k++) {
        int m = l + 4 * k;
        if (m < H) {
            float2 v = __half22float2(rn[m]);
            acc[k].x += v.x;
            acc[k].y += v.y;
            y2[(size_t)node * H + m] = acc[k];
        }
    }
}

// ---------------- layer-3 pass 2: gather h2b, add y, matmul 24x48, leaky, POOL ----------------
__global__ __launch_bounds__(256) void k_l3mm(
    const int* __restrict__ rowptr, const unsigned* __restrict__ pairs,
    const __half2* __restrict__ xb, const float2* __restrict__ y2,
    const float* __restrict__ dinv, const float* __restrict__ W,
    const float* __restrict__ b, float* __restrict__ g, int N) {
    constexpr int H = 6, FIN = 24, FOUT = 48, P = FOUT + 1;
    __shared__ float Ws[FIN * P];
    __shared__ float bs[FOUT];
    __shared__ float pool[FOUT];
    int t = threadIdx.x;
    for (int i = t; i < FIN * FOUT; i += 256) {
        int r = i / FOUT, c = i - r * FOUT;
        Ws[r * P + c] = W[i];
    }
    for (int i = t; i < FOUT; i += 256) {
        bs[i] = b[i];
        pool[i] = 0.0f;
    }
    __syncthreads();
    int stride = (int)(gridDim.x * blockDim.x);
    for (int idx = blockIdx.x * 256 + t; idx < N * 4; idx += stride) {
        int node = idx >> 2;
        int l = idx & 3;
        int beg = rowptr[node], end = rowptr[node + 1];
        float2 acc[2];
        acc[0] = make_float2(0.0f, 0.0f);
        acc[1] = make_float2(0.0f, 0.0f);
        int e = beg;
        for (; e + 4 <= end; e += 4) {
            unsigned q0 = pairs[e + 0], q1 = pairs[e + 1], q2 = pairs[e + 2], q3 = pairs[e + 3];
            const __half2* r0 = xb + (size_t)dec_s(q0) * H;
            const __half2* r1 = xb + (size_t)dec_s(q1) * H;
            const __half2* r2 = xb + (size_t)dec_s(q2) * H;
            const __half2* r3 = xb + (size_t)dec_s(q3) * H;
            float w0 = dec_w(q0), w1 = dec_w(q1), w2 = dec_w(q2), w3 = dec_w(q3);
#pragma unroll
            for (int k = 0; k < 2; k++) {
                int m = l + 4 * k;
                if (m < H) {
                    float2 v0 = __half22float2(r0[m]);
                    float2 v1 = __half22float2(r1[m]);
                    float2 v2 = __half22float2(r2[m]);
                    float2 v3 = __half22float2(r3[m]);
                    acc[k].x += v0.x * w0 + v1.x * w1 + v2.x * w2 + v3.x * w3;
                    acc[k].y += v0.y * w0 + v1.y * w1 + v2.y * w2 + v3.y * w3;
                }
            }
        }
        for (; e < end; e++) {
            unsigned q = pairs[e];
            const __half2* r = xb + (size_t)dec_s(q) * H;
            float w = dec_w(q);
#pragma unroll
            for (int k = 0; k < 2; k++) {
                int m = l + 4 * k;
                if (m < H) {
                    float2 v = __half22float2(r[m]);
                    acc[k].x += v.x * w;
                    acc[k].y += v.y * w;
                }
            }
        }
        const __half2* rn = xb + (size_t)node * H;
        float dv = dinv[node];
        float p[FOUT];
#pragma unroll
        for (int j = 0; j < FOUT; j++) p[j] = 0.0f;
#pragma unroll
        for (int k = 0; k < 2; k++) {
            int m = l + 4 * k;
            if (m < H) {
                float2 vs = __half22float2(rn[m]);
                float bx = acc[k].x + vs.x;   // aggregated features 12+2m, 12+2m+1
                float by = acc[k].y + vs.y;
                float2 ya = y2[(size_t)node * H + m];  // aggregated features 2m, 2m+1
                const float* wa0 = Ws + (2 * m) * P;
                const float* wa1 = Ws + (2 * m + 1) * P;
                const float* wb0 = Ws + (12 + 2 * m) * P;
                const float* wb1 = Ws + (12 + 2 * m + 1) * P;
#pragma unroll
                for (int j = 0; j < FOUT; j++)
                    p[j] += ya.x * wa0[j] + ya.y * wa1[j] + bx * wb0[j] + by * wb1[j];
            }
        }
#pragma unroll
        for (int j = 0; j < FOUT; j++) {
            p[j] += __shfl_xor(p[j], 1);
            p[j] += __shfl_xor(p[j], 2);
        }
        // pool: lane l owns columns j = l + 4q (each j added once per node)
#pragma unroll
        for (int q = 0; q < 12; q++) {
            int j = l + 4 * q;
            atomicAdd(&pool[j], leaky(dv * p[j] + bs[j]));
        }
    }
    __syncthreads();
    if (t < FOUT) atomicAdd(&g[t], pool[t]);
}

// ---------------- FC head: g[48] -> 32 -> 16 -> 2 ----------------
__global__ void k_head(const float* __restrict__ g,
                       const float* __restrict__ fcW1, const float* __restrict__ fcb1,
                       const float* __restrict__ fcW2, const float* __restrict__ fcb2,
                       const float* __restrict__ fcW3, const float* __restrict__ fcb3,
                       float* __restrict__ out) {
    __shared__ float gs[48], t1[32], t2[16];
    int t = threadIdx.x;
    if (t < 48) gs[t] = g[t];
    __syncthreads();
    if (t < 32) {
        float a = fcb1[t];
#pragma unroll
        for (int k = 0; k < 48; k++) a += gs[k] * fcW1[k * 32 + t];
        t1[t] = leaky(a);
    }
    __syncthreads();
    if (t < 16) {
        float a = fcb2[t];
#pragma unroll
        for (int k = 0; k < 32; k++) a += t1[k] * fcW2[k * 16 + t];
        t2[t] = leaky(a);
    }
    __syncthreads();
    if (t < 2) {
        float a = fcb3[t];
#pragma unroll
        for (int k = 0; k < 16; k++) a += t2[k] * fcW3[k * 2 + t];
        out[t] = a;
    }
}

extern "C" void kernel_launch(void* const* d_in, const int* in_sizes, int n_in,
                              void* d_out, int out_size, void* d_ws, size_t ws_size,
                              hipStream_t stream) {
    const float* xin = (const float*)d_in[0];   // [N,4]
    const float* ew  = (const float*)d_in[1];   // [E]
    const int*   ei  = (const int*)d_in[2];     // [2,E]
    const float* W1  = (const float*)d_in[3];
    const float* b1  = (const float*)d_in[4];
    const float* W2  = (const float*)d_in[5];
    const float* b2  = (const float*)d_in[6];
    const float* W3  = (const float*)d_in[7];
    const float* b3  = (const float*)d_in[8];
    const float* fcW1 = (const float*)d_in[9];
    const float* fcb1 = (const float*)d_in[10];
    const float* fcW2 = (const float*)d_in[11];
    const float* fcb2 = (const float*)d_in[12];
    const float* fcW3 = (const float*)d_in[13];
    const float* fcb3 = (const float*)d_in[14];

    const int N = in_sizes[0] / 4;
    const int E = in_sizes[1];
    const int* src = ei;
    const int* dst = ei + E;
    const int nbins = (N + 255) >> 8;      // 391 for N=100k
    const int EPB = cdiv(E, NBLK);

    // workspace layout, 16B-aligned chunks
    char* p_ = (char*)d_ws;
    auto alloc = [&](size_t bytes) { char* r = p_; p_ += (bytes + 15) & ~(size_t)15; return r; };
    unsigned* sortedP = (unsigned*)alloc((size_t)E * 4);
    unsigned* pairs   = (unsigned*)alloc((size_t)E * 4);
    unsigned char* sortedDlo = (unsigned char*)alloc((size_t)E);
    int*   hist    = (int*)alloc((size_t)BINS_MAX * NBLK * 4);
    int*   binTot  = (int*)alloc((size_t)BINS_MAX * 4);
    int*   binBase = (int*)alloc((size_t)(BINS_MAX + 1) * 4);
    int*   rowptr  = (int*)alloc((size_t)(N + 1) * 4);
    float* dinv    = (float*)alloc((size_t)N * 4);
    __half2* x0h   = (__half2*)alloc((size_t)N * 2 * 4);   // [N][2]  x~0
    __half2* h1    = (__half2*)alloc((size_t)N * 6 * 4);   // [N][6]  x~1
    __half2* h2a   = (__half2*)alloc((size_t)N * 6 * 4);   // [N][6]  x~2 feats 0-11
    __half2* h2b   = (__half2*)alloc((size_t)N * 6 * 4);   // [N][6]  x~2 feats 12-23
    float2* y12    = (float2*)alloc((size_t)N * 6 * 8);    // [N][6]  layer3 partial agg
    float* g       = (float*)alloc(48 * 4);

    // --- sort-based CSR build + node stats (no fabric atomics) ---
    k_hist<<<NBLK, BT, 0, stream>>>(dst, hist, E, EPB, nbins);
    k_scan_cols<<<nbins, BT, 0, stream>>>(hist, binTot);
    k_scan_bins<<<1, BT, 0, stream>>>(binTot, binBase, nbins);
    k_scatter_bins<<<NBLK, BT, 0, stream>>>(src, dst, ew, hist, binBase,
                                            sortedP, sortedDlo, E, EPB, nbins);
    k_bin_sort<<<nbins, BT, 0, stream>>>(sortedP, sortedDlo, binBase, xin,
                                         pairs, rowptr, dinv, x0h, N, E);

    // --- layers 1,2 (fused gather+matmul), layer-2 output split into h2a/h2b ---
    k_layer<4, 12, 6, 2><<<cdiv((long long)N * 2, 256), 256, 0, stream>>>(
        rowptr, pairs, x0h, dinv, W1, b1, h1, h1, N);
    k_layer<12, 24, 6, 4><<<cdiv((long long)N * 4, 256), 256, 0, stream>>>(
        rowptr, pairs, h1, dinv, W2, b2, h2a, h2b, N);

    // --- layer 3: agg pass (feats 0-11) + gather/matmul/pool pass (feats 12-23) ---
    k_agg<<<cdiv((long long)N * 4, 256), 256, 0, stream>>>(rowptr, pairs, h2a, y12, N);
    hipMemsetAsync(g, 0, 48 * sizeof(float), stream);
    k_l3mm<<<784, 256, 0, stream>>>(rowptr, pairs, h2b, y12, dinv, W3, b3, g, N);

    // --- FC head ---
    k_head<<<1, 64, 0, stream>>>(g, fcW1, fcb1, fcW2, fcb2, fcW3, fcb3, (float*)d_out);
}

// Round 7
// 256.771 us; speedup vs baseline: 1.1980x; 1.1980x over previous
//
#include <hip/hip_runtime.h>
#include <hip/hip_bf16.h>
#include <hip/hip_fp16.h>

static inline int cdiv(long long a, int b) { return (int)((a + b - 1) / b); }

#define LEAK 0.1f
__device__ __forceinline__ float leaky(float v) { return v >= 0.0f ? v : LEAK * v; }

// packed edge: bits[31:15] = src (17b), bits[14:0] = fp16(w) >> 1
__device__ __forceinline__ int dec_s(unsigned p) { return (int)(p >> 15); }
__device__ __forceinline__ float dec_w(unsigned p) {
    return __half2float(__ushort_as_half((unsigned short)((p & 0x7FFFu) << 1)));
}
__device__ __forceinline__ unsigned enc_sw(int s, float w) {
    return ((unsigned)s << 15) | ((unsigned)__half_as_ushort(__float2half_rn(w)) >> 1);
}

constexpr int BT = 256;        // threads per block (all build kernels)
constexpr int NBLK = 512;      // edge-partition blocks (phases A/C)
constexpr int CHUNK = 4096;    // edges staged in LDS per pass (phase C)
constexpr int BINS_MAX = 512;  // >= (N+255)/256 for N=100k (391)

// ---------------- phase A: per-(bin, block) histogram of dst>>8 ----------------
__global__ __launch_bounds__(BT) void k_hist(const int* __restrict__ dst, int* __restrict__ hist,
                                             int E, int EPB, int nbins) {
    __shared__ int h[BINS_MAX];
    for (int i = threadIdx.x; i < nbins; i += BT) h[i] = 0;
    __syncthreads();
    int base = blockIdx.x * EPB;
    int end = min(base + EPB, E);
    for (int i = base + threadIdx.x; i < end; i += BT) atomicAdd(&h[dst[i] >> 8], 1);
    __syncthreads();
    for (int i = threadIdx.x; i < nbins; i += BT) hist[(size_t)i * NBLK + blockIdx.x] = h[i];
}

// ---------------- phase B1: exclusive scan of each bin's row over blocks ----------------
__global__ __launch_bounds__(BT) void k_scan_cols(int* __restrict__ hist, int* __restrict__ binTot) {
    __shared__ int a[NBLK], b_[NBLK];
    int t = threadIdx.x;
    int* H = hist + (size_t)blockIdx.x * NBLK;
    for (int i = t; i < NBLK; i += BT) a[i] = H[i];
    __syncthreads();
    int* cur = a; int* nxt = b_;
    for (int off = 1; off < NBLK; off <<= 1) {
        for (int i = t; i < NBLK; i += BT) nxt[i] = cur[i] + (i >= off ? cur[i - off] : 0);
        __syncthreads();
        int* tm = cur; cur = nxt; nxt = tm;
    }
    for (int i = t; i < NBLK; i += BT) H[i] = (i ? cur[i - 1] : 0);
    if (t == 0) binTot[blockIdx.x] = cur[NBLK - 1];
}

// ---------------- phase B2: exclusive scan over bins ----------------
__global__ __launch_bounds__(BT) void k_scan_bins(const int* __restrict__ binTot,
                                                  int* __restrict__ binBase, int nbins) {
    __shared__ int a[BINS_MAX], b_[BINS_MAX];
    int t = threadIdx.x;
    for (int i = t; i < BINS_MAX; i += BT) a[i] = (i < nbins) ? binTot[i] : 0;
    __syncthreads();
    int* cur = a; int* nxt = b_;
    for (int off = 1; off < BINS_MAX; off <<= 1) {
        for (int i = t; i < BINS_MAX; i += BT) nxt[i] = cur[i] + (i >= off ? cur[i - off] : 0);
        __syncthreads();
        int* tm = cur; cur = nxt; nxt = tm;
    }
    for (int i = t; i < nbins; i += BT) binBase[i] = (i ? cur[i - 1] : 0);
    if (t == 0) binBase[nbins] = cur[nbins - 1];  // == E
}

// ---------------- phase C: LDS-staged scatter of edges into bin order ----------------
__global__ __launch_bounds__(BT) void k_scatter_bins(
    const int* __restrict__ src, const int* __restrict__ dst, const float* __restrict__ ew,
    const int* __restrict__ colOff, const int* __restrict__ binBase,
    unsigned* __restrict__ sortedP, unsigned char* __restrict__ sortedDlo,
    int E, int EPB, int nbins) {
    constexpr int EPT = CHUNK / BT;  // 16 edges per thread per chunk
    __shared__ unsigned sP[CHUNK];        // 16 KB
    __shared__ unsigned char sD[CHUNK];   // 4 KB
    __shared__ unsigned short sB[CHUNK];  // 8 KB
    __shared__ int h[BINS_MAX], sc[BINS_MAX], sc2[BINS_MAX];
    __shared__ int blkOff[BINS_MAX], cursor[BINS_MAX];

    int t = threadIdx.x, blk = blockIdx.x;
    for (int i = t; i < nbins; i += BT) {
        blkOff[i] = binBase[i] + colOff[(size_t)i * NBLK + blk];
        cursor[i] = 0;
    }
    int base = blk * EPB;
    int bend = min(base + EPB, E);
    for (int cb = base; cb < bend; cb += CHUNK) {
        int cnt = min(CHUNK, bend - cb);
        for (int i = t; i < nbins; i += BT) h[i] = 0;
        __syncthreads();
        int myBin[EPT], myRank[EPT], myD[EPT];
        unsigned myP[EPT];
#pragma unroll
        for (int k = 0; k < EPT; k++) {
            int li = k * BT + t;
            if (li < cnt) {
                int i = cb + li;
                int d = dst[i];
                myP[k] = enc_sw(src[i], ew[i]);
                myD[k] = d & 255;
                int b = d >> 8;
                myBin[k] = b;
                myRank[k] = atomicAdd(&h[b], 1);
            } else myBin[k] = -1;
        }
        __syncthreads();
        for (int i = t; i < BINS_MAX; i += BT) sc[i] = (i < nbins) ? h[i] : 0;
        __syncthreads();
        int* cur = sc; int* nxt = sc2;
        for (int off = 1; off < BINS_MAX; off <<= 1) {
            for (int i = t; i < BINS_MAX; i += BT) nxt[i] = cur[i] + (i >= off ? cur[i - off] : 0);
            __syncthreads();
            int* tm = cur; cur = nxt; nxt = tm;
        }
#pragma unroll
        for (int k = 0; k < EPT; k++) {
            int b = myBin[k];
            if (b >= 0) {
                int pos = (b ? cur[b - 1] : 0) + myRank[k];
                sP[pos] = myP[k];
                sD[pos] = (unsigned char)myD[k];
                sB[pos] = (unsigned short)b;
            }
        }
        __syncthreads();
        for (int i = t; i < cnt; i += BT) {
            int b = sB[i];
            int excl = (b ? cur[b - 1] : 0);
            int g = blkOff[b] + cursor[b] + (i - excl);
            sortedP[g] = sP[i];
            sortedDlo[g] = sD[i];
        }
        __syncthreads();
        for (int i = t; i < nbins; i += BT) cursor[i] += h[i];
        __syncthreads();
    }
}

// ---------------- phase D: per-bin counting sort -> CSR, plus node stats ----------------
__global__ __launch_bounds__(BT) void k_bin_sort(
    const unsigned* __restrict__ sortedP, const unsigned char* __restrict__ sortedDlo,
    const int* __restrict__ binBase, const float* __restrict__ xin,
    unsigned* __restrict__ pairs, int* __restrict__ rowptr,
    float* __restrict__ dinv, __half2* __restrict__ x0h, int N, int E) {
    __shared__ int cnt[256], a[256], b_[256], cursor[256];
    __shared__ float degs[256];
    int bin = blockIdx.x, t = threadIdx.x;  // BT == 256
    int e0 = binBase[bin], e1 = binBase[bin + 1];
    int nodeBase = bin << 8;
    int nn = min(256, N - nodeBase);
    cnt[t] = 0;
    degs[t] = 0.0f;
    __syncthreads();
    for (int i = e0 + t; i < e1; i += BT) atomicAdd(&cnt[sortedDlo[i]], 1);
    __syncthreads();
    a[t] = cnt[t];
    __syncthreads();
    int* cur = a; int* nxt = b_;
    for (int off = 1; off < 256; off <<= 1) {
        nxt[t] = cur[t] + (t >= off ? cur[t - off] : 0);
        __syncthreads();
        int* tm = cur; cur = nxt; nxt = tm;
    }
    int ex = (t ? cur[t - 1] : 0);
    if (t < nn) rowptr[nodeBase + t] = e0 + ex;
    __syncthreads();
    cnt[t] = ex;   // repurpose: exclusive offset per local node
    cursor[t] = 0;
    __syncthreads();
    for (int i = e0 + t; i < e1; i += BT) {
        int dl = sortedDlo[i];
        unsigned v = sortedP[i];
        atomicAdd(&degs[dl], dec_w(v));
        int r = atomicAdd(&cursor[dl], 1);
        pairs[e0 + cnt[dl] + r] = v;
    }
    __syncthreads();
    if (t < nn) {
        int node = nodeBase + t;
        float d = 1.0f + degs[t];
        float di = rsqrtf(d);
        dinv[node] = di;
        float4 xv = *reinterpret_cast<const float4*>(xin + (size_t)node * 4);
        x0h[(size_t)node * 2 + 0] = __floats2half2_rn(xv.x * di, xv.y * di);
        x0h[(size_t)node * 2 + 1] = __floats2half2_rn(xv.z * di, xv.w * di);
    }
    if (bin == 0 && t == 0) rowptr[N] = E;
}

// ---------------- fused layer (layers 1,2): lane-split output columns ----------------
// x~ fp16 rows (H=FIN/2 half2). TPN lanes per node; lane l owns input pairs m=l+TPN*k
// and output columns j=l+TPN*q. Broadcast inputs via width-TPN shfl (const reg idx).
// out feature j: x~' = dinv * leaky(dv*agg@W + b), scalar half store, split at SPLIT.
template <int FIN, int FOUT, int TPN, int SPLIT>
__global__ void k_layer(const int* __restrict__ rowptr, const unsigned* __restrict__ pairs,
                        const __half2* __restrict__ x, const float* __restrict__ dinv,
                        const float* __restrict__ W, const float* __restrict__ b,
                        __half* __restrict__ outA, __half* __restrict__ outB, int N) {
    constexpr int H = FIN / 2;
    constexpr int P = FOUT + 1;
    constexpr int KX = (H + TPN - 1) / TPN;
    constexpr int CPL = FOUT / TPN;  // columns per lane
    __shared__ float Ws[FIN * P];
    __shared__ float bs[FOUT];
    for (int t = threadIdx.x; t < FIN * FOUT; t += blockDim.x) {
        int r = t / FOUT, c = t - r * FOUT;
        Ws[r * P + c] = W[t];
    }
    for (int t = threadIdx.x; t < FOUT; t += blockDim.x) bs[t] = b[t];
    __syncthreads();
    int gid = blockIdx.x * blockDim.x + threadIdx.x;
    int node = gid / TPN;
    int l = gid & (TPN - 1);
    if (node >= N) return;
    int beg = rowptr[node], end = rowptr[node + 1];

    float2 acc[KX];
#pragma unroll
    for (int k = 0; k < KX; k++) acc[k] = make_float2(0.0f, 0.0f);

    int e = beg;
    for (; e + 4 <= end; e += 4) {
        unsigned q0 = pairs[e + 0], q1 = pairs[e + 1], q2 = pairs[e + 2], q3 = pairs[e + 3];
        const __half2* r0 = x + (size_t)dec_s(q0) * H;
        const __half2* r1 = x + (size_t)dec_s(q1) * H;
        const __half2* r2 = x + (size_t)dec_s(q2) * H;
        const __half2* r3 = x + (size_t)dec_s(q3) * H;
        float w0 = dec_w(q0), w1 = dec_w(q1), w2 = dec_w(q2), w3 = dec_w(q3);
#pragma unroll
        for (int k = 0; k < KX; k++) {
            int m = l + TPN * k;
            if (m < H) {
                float2 v0 = __half22float2(r0[m]);
                float2 v1 = __half22float2(r1[m]);
                float2 v2 = __half22float2(r2[m]);
                float2 v3 = __half22float2(r3[m]);
                acc[k].x += v0.x * w0 + v1.x * w1 + v2.x * w2 + v3.x * w3;
                acc[k].y += v0.y * w0 + v1.y * w1 + v2.y * w2 + v3.y * w3;
            }
        }
    }
    for (; e < end; e++) {
        unsigned q = pairs[e];
        const __half2* r = x + (size_t)dec_s(q) * H;
        float w = dec_w(q);
#pragma unroll
        for (int k = 0; k < KX; k++) {
            int m = l + TPN * k;
            if (m < H) {
                float2 v = __half22float2(r[m]);
                acc[k].x += v.x * w;
                acc[k].y += v.y * w;
            }
        }
    }
    {   // self-loop (weight 1)
        const __half2* rn = x + (size_t)node * H;
#pragma unroll
        for (int k = 0; k < KX; k++) {
            int m = l + TPN * k;
            if (m < H) {
                float2 v = __half22float2(rn[m]);
                acc[k].x += v.x;
                acc[k].y += v.y;
            }
        }
    }
    float dv = dinv[node];
    float p[CPL];
#pragma unroll
    for (int q = 0; q < CPL; q++) p[q] = 0.0f;
#pragma unroll
    for (int m = 0; m < H; m++) {       // broadcast owned pairs to the group
        float ax = __shfl(acc[m / TPN].x, m % TPN, TPN);
        float ay = __shfl(acc[m / TPN].y, m % TPN, TPN);
        const float* w0r = Ws + (2 * m) * P;
        const float* w1r = Ws + (2 * m + 1) * P;
#pragma unroll
        for (int q = 0; q < CPL; q++) {
            int j = l + TPN * q;
            p[q] += ax * w0r[j] + ay * w1r[j];
        }
    }
#pragma unroll
    for (int q = 0; q < CPL; q++) {
        int j = l + TPN * q;
        float a = leaky(dv * p[q] + bs[j]) * dv;
        __half hv = __float2half_rn(a);
        if (j < SPLIT) outA[(size_t)node * SPLIT + j] = hv;
        else outB[(size_t)node * (FOUT - SPLIT) + (j - SPLIT)] = hv;
    }
}

// ---------------- layer-3 pass 1: aggregate features 0-11 from h2a ----------------
__global__ void k_agg(const int* __restrict__ rowptr, const unsigned* __restrict__ pairs,
                      const __half2* __restrict__ xa, float2* __restrict__ y2, int N) {
    constexpr int H = 6;
    int gid = blockIdx.x * blockDim.x + threadIdx.x;
    int node = gid >> 2;
    int l = gid & 3;
    if (node >= N) return;
    int beg = rowptr[node], end = rowptr[node + 1];
    float2 acc[2];
    acc[0] = make_float2(0.0f, 0.0f);
    acc[1] = make_float2(0.0f, 0.0f);
    int e = beg;
    for (; e + 4 <= end; e += 4) {
        unsigned q0 = pairs[e + 0], q1 = pairs[e + 1], q2 = pairs[e + 2], q3 = pairs[e + 3];
        const __half2* r0 = xa + (size_t)dec_s(q0) * H;
        const __half2* r1 = xa + (size_t)dec_s(q1) * H;
        const __half2* r2 = xa + (size_t)dec_s(q2) * H;
        const __half2* r3 = xa + (size_t)dec_s(q3) * H;
        float w0 = dec_w(q0), w1 = dec_w(q1), w2 = dec_w(q2), w3 = dec_w(q3);
#pragma unroll
        for (int k = 0; k < 2; k++) {
            int m = l + 4 * k;
            if (m < H) {
                float2 v0 = __half22float2(r0[m]);
                float2 v1 = __half22float2(r1[m]);
                float2 v2 = __half22float2(r2[m]);
                float2 v3 = __half22float2(r3[m]);
                acc[k].x += v0.x * w0 + v1.x * w1 + v2.x * w2 + v3.x * w3;
                acc[k].y += v0.y * w0 + v1.y * w1 + v2.y * w2 + v3.y * w3;
            }
        }
    }
    for (; e < end; e++) {
        unsigned q = pairs[e];
        const __half2* r = xa + (size_t)dec_s(q) * H;
        float w = dec_w(q);
#pragma unroll
        for (int k = 0; k < 2; k++) {
            int m = l + 4 * k;
            if (m < H) {
                float2 v = __half22float2(r[m]);
                acc[k].x += v.x * w;
                acc[k].y += v.y * w;
            }
        }
    }
    const __half2* rn = xa + (size_t)node * H;
#pragma unroll
    for (int k = 0; k < 2; k++) {
        int m = l + 4 * k;
        if (m < H) {
            float2 v = __half22float2(rn[m]);
            acc[k].x += v.x;
            acc[k].y += v.y;
            y2[(size_t)node * H + m] = acc[k];
        }
    }
}

// ---------------- layer-3 pass 2: gather h2b, + y12, 24x48 matmul, leaky, pool ----------------
// Lane-split: lane l owns output columns j = l+4q (q=0..11). Inputs broadcast via shfl.
__global__ __launch_bounds__(256) void k_l3mm(
    const int* __restrict__ rowptr, const unsigned* __restrict__ pairs,
    const __half2* __restrict__ xb, const float2* __restrict__ y2,
    const float* __restrict__ dinv, const float* __restrict__ W,
    const float* __restrict__ b, float* __restrict__ g, int N) {
    constexpr int H = 6, FOUT = 48, P = FOUT + 1, CPL = 12;
    __shared__ float Ws[24 * P];
    __shared__ float bs[FOUT];
    __shared__ float pool[FOUT];
    int t = threadIdx.x;
    for (int i = t; i < 24 * FOUT; i += 256) {
        int r = i / FOUT, c = i - r * FOUT;
        Ws[r * P + c] = W[i];
    }
    for (int i = t; i < FOUT; i += 256) {
        bs[i] = b[i];
        pool[i] = 0.0f;
    }
    __syncthreads();
    int l = t & 3;
    float pacc[CPL];
#pragma unroll
    for (int q = 0; q < CPL; q++) pacc[q] = 0.0f;

    int stride = (int)(gridDim.x * blockDim.x);  // multiple of 4
    for (int idx = blockIdx.x * 256 + t; idx < N * 4; idx += stride) {
        int node = idx >> 2;
        int beg = rowptr[node], end = rowptr[node + 1];
        float2 acc[2];
        acc[0] = make_float2(0.0f, 0.0f);
        acc[1] = make_float2(0.0f, 0.0f);
        int e = beg;
        for (; e + 4 <= end; e += 4) {
            unsigned q0 = pairs[e + 0], q1 = pairs[e + 1], q2 = pairs[e + 2], q3 = pairs[e + 3];
            const __half2* r0 = xb + (size_t)dec_s(q0) * H;
            const __half2* r1 = xb + (size_t)dec_s(q1) * H;
            const __half2* r2 = xb + (size_t)dec_s(q2) * H;
            const __half2* r3 = xb + (size_t)dec_s(q3) * H;
            float w0 = dec_w(q0), w1 = dec_w(q1), w2 = dec_w(q2), w3 = dec_w(q3);
#pragma unroll
            for (int k = 0; k < 2; k++) {
                int m = l + 4 * k;
                if (m < H) {
                    float2 v0 = __half22float2(r0[m]);
                    float2 v1 = __half22float2(r1[m]);
                    float2 v2 = __half22float2(r2[m]);
                    float2 v3 = __half22float2(r3[m]);
                    acc[k].x += v0.x * w0 + v1.x * w1 + v2.x * w2 + v3.x * w3;
                    acc[k].y += v0.y * w0 + v1.y * w1 + v2.y * w2 + v3.y * w3;
                }
            }
        }
        for (; e < end; e++) {
            unsigned q = pairs[e];
            const __half2* r = xb + (size_t)dec_s(q) * H;
            float w = dec_w(q);
#pragma unroll
            for (int k = 0; k < 2; k++) {
                int m = l + 4 * k;
                if (m < H) {
                    float2 v = __half22float2(r[m]);
                    acc[k].x += v.x * w;
                    acc[k].y += v.y * w;
                }
            }
        }
        // self-loop + y12 load (owned slots m = l+4k)
        const __half2* rn = xb + (size_t)node * H;
        float2 ya[2];
#pragma unroll
        for (int k = 0; k < 2; k++) {
            int m = l + 4 * k;
            if (m < H) {
                float2 v = __half22float2(rn[m]);
                acc[k].x += v.x;
                acc[k].y += v.y;
                ya[k] = y2[(size_t)node * H + m];
            } else ya[k] = make_float2(0.0f, 0.0f);
        }
        float dv = dinv[node];
        float p[CPL];
#pragma unroll
        for (int q = 0; q < CPL; q++) p[q] = 0.0f;
        // A-half: features 0-11 (y12), rows 0..11 of W
#pragma unroll
        for (int m = 0; m < H; m++) {
            float ax = __shfl(ya[m / 4].x, m % 4, 4);
            float ay = __shfl(ya[m / 4].y, m % 4, 4);
            const float* w0r = Ws + (2 * m) * P;
            const float* w1r = Ws + (2 * m + 1) * P;
#pragma unroll
            for (int q = 0; q < CPL; q++) {
                int j = l + 4 * q;
                p[q] += ax * w0r[j] + ay * w1r[j];
            }
        }
        // B-half: features 12-23 (acc), rows 12..23 of W
#pragma unroll
        for (int m = 0; m < H; m++) {
            float bx = __shfl(acc[m / 4].x, m % 4, 4);
            float by = __shfl(acc[m / 4].y, m % 4, 4);
            const float* w0r = Ws + (12 + 2 * m) * P;
            const float* w1r = Ws + (12 + 2 * m + 1) * P;
#pragma unroll
            for (int q = 0; q < CPL; q++) {
                int j = l + 4 * q;
                p[q] += bx * w0r[j] + by * w1r[j];
            }
        }
#pragma unroll
        for (int q = 0; q < CPL; q++) pacc[q] += leaky(dv * p[q] + bs[l + 4 * q]);
    }
#pragma unroll
    for (int q = 0; q < CPL; q++) atomicAdd(&pool[l + 4 * q], pacc[q]);
    __syncthreads();
    if (t < FOUT) atomicAdd(&g[t], pool[t]);
}

// ---------------- FC head: g[48] -> 32 -> 16 -> 2 ----------------
__global__ void k_head(const float* __restrict__ g,
                       const float* __restrict__ fcW1, const float* __restrict__ fcb1,
                       const float* __restrict__ fcW2, const float* __restrict__ fcb2,
                       const float* __restrict__ fcW3, const float* __restrict__ fcb3,
                       float* __restrict__ out) {
    __shared__ float gs[48], t1[32], t2[16];
    int t = threadIdx.x;
    if (t < 48) gs[t] = g[t];
    __syncthreads();
    if (t < 32) {
        float a = fcb1[t];
#pragma unroll
        for (int k = 0; k < 48; k++) a += gs[k] * fcW1[k * 32 + t];
        t1[t] = leaky(a);
    }
    __syncthreads();
    if (t < 16) {
        float a = fcb2[t];
#pragma unroll
        for (int k = 0; k < 32; k++) a += t1[k] * fcW2[k * 16 + t];
        t2[t] = leaky(a);
    }
    __syncthreads();
    if (t < 2) {
        float a = fcb3[t];
#pragma unroll
        for (int k = 0; k < 16; k++) a += t2[k] * fcW3[k * 2 + t];
        out[t] = a;
    }
}

extern "C" void kernel_launch(void* const* d_in, const int* in_sizes, int n_in,
                              void* d_out, int out_size, void* d_ws, size_t ws_size,
                              hipStream_t stream) {
    const float* xin = (const float*)d_in[0];   // [N,4]
    const float* ew  = (const float*)d_in[1];   // [E]
    const int*   ei  = (const int*)d_in[2];     // [2,E]
    const float* W1  = (const float*)d_in[3];
    const float* b1  = (const float*)d_in[4];
    const float* W2  = (const float*)d_in[5];
    const float* b2  = (const float*)d_in[6];
    const float* W3  = (const float*)d_in[7];
    const float* b3  = (const float*)d_in[8];
    const float* fcW1 = (const float*)d_in[9];
    const float* fcb1 = (const float*)d_in[10];
    const float* fcW2 = (const float*)d_in[11];
    const float* fcb2 = (const float*)d_in[12];
    const float* fcW3 = (const float*)d_in[13];
    const float* fcb3 = (const float*)d_in[14];

    const int N = in_sizes[0] / 4;
    const int E = in_sizes[1];
    const int* src = ei;
    const int* dst = ei + E;
    const int nbins = (N + 255) >> 8;      // 391 for N=100k
    const int EPB = cdiv(E, NBLK);

    // workspace layout, 16B-aligned chunks
    char* p_ = (char*)d_ws;
    auto alloc = [&](size_t bytes) { char* r = p_; p_ += (bytes + 15) & ~(size_t)15; return r; };
    unsigned* sortedP = (unsigned*)alloc((size_t)E * 4);
    unsigned* pairs   = (unsigned*)alloc((size_t)E * 4);
    unsigned char* sortedDlo = (unsigned char*)alloc((size_t)E);
    int*   hist    = (int*)alloc((size_t)BINS_MAX * NBLK * 4);
    int*   binTot  = (int*)alloc((size_t)BINS_MAX * 4);
    int*   binBase = (int*)alloc((size_t)(BINS_MAX + 1) * 4);
    int*   rowptr  = (int*)alloc((size_t)(N + 1) * 4);
    float* dinv    = (float*)alloc((size_t)N * 4);
    __half2* x0h   = (__half2*)alloc((size_t)N * 2 * 4);   // [N][2]  x~0
    __half*  h1    = (__half*)alloc((size_t)N * 12 * 2);   // [N][12] x~1
    __half*  h2a   = (__half*)alloc((size_t)N * 12 * 2);   // [N][12] x~2 feats 0-11
    __half*  h2b   = (__half*)alloc((size_t)N * 12 * 2);   // [N][12] x~2 feats 12-23
    float2* y12    = (float2*)alloc((size_t)N * 6 * 8);    // [N][6]  layer3 partial agg
    float* g       = (float*)alloc(48 * 4);

    // --- sort-based CSR build + node stats (no fabric atomics) ---
    k_hist<<<NBLK, BT, 0, stream>>>(dst, hist, E, EPB, nbins);
    k_scan_cols<<<nbins, BT, 0, stream>>>(hist, binTot);
    k_scan_bins<<<1, BT, 0, stream>>>(binTot, binBase, nbins);
    k_scatter_bins<<<NBLK, BT, 0, stream>>>(src, dst, ew, hist, binBase,
                                            sortedP, sortedDlo, E, EPB, nbins);
    k_bin_sort<<<nbins, BT, 0, stream>>>(sortedP, sortedDlo, binBase, xin,
                                         pairs, rowptr, dinv, x0h, N, E);

    // --- layers 1,2 (lane-split matmul), layer-2 output split into h2a/h2b ---
    k_layer<4, 12, 2, 12><<<cdiv((long long)N * 2, 256), 256, 0, stream>>>(
        rowptr, pairs, x0h, dinv, W1, b1, h1, h1, N);
    k_layer<12, 24, 4, 12><<<cdiv((long long)N * 4, 256), 256, 0, stream>>>(
        rowptr, pairs, (const __half2*)h1, dinv, W2, b2, h2a, h2b, N);

    // --- layer 3: agg pass (feats 0-11) + gather/matmul/pool pass (feats 12-23) ---
    k_agg<<<cdiv((long long)N * 4, 256), 256, 0, stream>>>(
        rowptr, pairs, (const __half2*)h2a, y12, N);
    hipMemsetAsync(g, 0, 48 * sizeof(float), stream);
    k_l3mm<<<512, 256, 0, stream>>>(rowptr, pairs, (const __half2*)h2b, y12, dinv, W3, b3, g, N);

    // --- FC head ---
    k_head<<<1, 64, 0, stream>>>(g, fcW1, fcb1, fcW2, fcb2, fcW3, fcb3, (float*)d_out);
}

// Round 8
// 245.707 us; speedup vs baseline: 1.2520x; 1.0450x over previous
//
#include <hip/hip_runtime.h>
#include <hip/hip_bf16.h>
#include <hip/hip_fp16.h>

static inline int cdiv(long long a, int b) { return (int)((a + b - 1) / b); }

#define LEAK 0.1f
__device__ __forceinline__ float leaky(float v) { return v >= 0.0f ? v : LEAK * v; }

// packed edge: bits[31:15] = src (17b), bits[14:0] = fp16(w) >> 1 ; 0 == zero-pad edge
__device__ __forceinline__ int dec_s(unsigned p) { return (int)(p >> 15); }
__device__ __forceinline__ float dec_w(unsigned p) {
    return __half2float(__ushort_as_half((unsigned short)((p & 0x7FFFu) << 1)));
}
__device__ __forceinline__ unsigned enc_sw(int s, float w) {
    return ((unsigned)s << 15) | ((unsigned)__half_as_ushort(__float2half_rn(w)) >> 1);
}

constexpr int BT = 256;        // threads per block (build kernels)
constexpr int NBLK = 512;      // edge-partition blocks (phases A/C)
constexpr int CHUNK = 4096;    // edges staged in LDS per pass (phase C)
constexpr int BINS_MAX = 512;  // >= (N+255)/256 for N=100k (391)
constexpr int BIN_PAD = 1024;  // per-bin slack in pairs[] for row padding

// ---------------- phase A: per-(bin, block) histogram of dst>>8 ----------------
__global__ __launch_bounds__(BT) void k_hist(const int* __restrict__ dst, int* __restrict__ hist,
                                             int E, int EPB, int nbins) {
    __shared__ int h[BINS_MAX];
    for (int i = threadIdx.x; i < nbins; i += BT) h[i] = 0;
    __syncthreads();
    int base = blockIdx.x * EPB;
    int end = min(base + EPB, E);
    for (int i = base + threadIdx.x; i < end; i += BT) atomicAdd(&h[dst[i] >> 8], 1);
    __syncthreads();
    for (int i = threadIdx.x; i < nbins; i += BT) hist[(size_t)i * NBLK + blockIdx.x] = h[i];
}

// ---------------- phase B1: exclusive scan of each bin's row over blocks ----------------
__global__ __launch_bounds__(BT) void k_scan_cols(int* __restrict__ hist, int* __restrict__ binTot) {
    __shared__ int a[NBLK], b_[NBLK];
    int t = threadIdx.x;
    int* H = hist + (size_t)blockIdx.x * NBLK;
    for (int i = t; i < NBLK; i += BT) a[i] = H[i];
    __syncthreads();
    int* cur = a; int* nxt = b_;
    for (int off = 1; off < NBLK; off <<= 1) {
        for (int i = t; i < NBLK; i += BT) nxt[i] = cur[i] + (i >= off ? cur[i - off] : 0);
        __syncthreads();
        int* tm = cur; cur = nxt; nxt = tm;
    }
    for (int i = t; i < NBLK; i += BT) H[i] = (i ? cur[i - 1] : 0);
    if (t == 0) binTot[blockIdx.x] = cur[NBLK - 1];
}

// ---------------- phase B2: exclusive scan over bins ----------------
__global__ __launch_bounds__(BT) void k_scan_bins(const int* __restrict__ binTot,
                                                  int* __restrict__ binBase, int nbins) {
    __shared__ int a[BINS_MAX], b_[BINS_MAX];
    int t = threadIdx.x;
    for (int i = t; i < BINS_MAX; i += BT) a[i] = (i < nbins) ? binTot[i] : 0;
    __syncthreads();
    int* cur = a; int* nxt = b_;
    for (int off = 1; off < BINS_MAX; off <<= 1) {
        for (int i = t; i < BINS_MAX; i += BT) nxt[i] = cur[i] + (i >= off ? cur[i - off] : 0);
        __syncthreads();
        int* tm = cur; cur = nxt; nxt = tm;
    }
    for (int i = t; i < nbins; i += BT) binBase[i] = (i ? cur[i - 1] : 0);
    if (t == 0) binBase[nbins] = cur[nbins - 1];  // == E
}

// ---------------- phase C: LDS-staged scatter of edges into bin order ----------------
__global__ __launch_bounds__(BT) void k_scatter_bins(
    const int* __restrict__ src, const int* __restrict__ dst, const float* __restrict__ ew,
    const int* __restrict__ colOff, const int* __restrict__ binBase,
    unsigned* __restrict__ sortedP, unsigned char* __restrict__ sortedDlo,
    int E, int EPB, int nbins) {
    constexpr int EPT = CHUNK / BT;  // 16 edges per thread per chunk
    __shared__ unsigned sP[CHUNK];        // 16 KB
    __shared__ unsigned char sD[CHUNK];   // 4 KB
    __shared__ unsigned short sB[CHUNK];  // 8 KB
    __shared__ int h[BINS_MAX], sc[BINS_MAX], sc2[BINS_MAX];
    __shared__ int blkOff[BINS_MAX], cursor[BINS_MAX];

    int t = threadIdx.x, blk = blockIdx.x;
    for (int i = t; i < nbins; i += BT) {
        blkOff[i] = binBase[i] + colOff[(size_t)i * NBLK + blk];
        cursor[i] = 0;
    }
    int base = blk * EPB;
    int bend = min(base + EPB, E);
    for (int cb = base; cb < bend; cb += CHUNK) {
        int cnt = min(CHUNK, bend - cb);
        for (int i = t; i < nbins; i += BT) h[i] = 0;
        __syncthreads();
        int myBin[EPT], myRank[EPT], myD[EPT];
        unsigned myP[EPT];
#pragma unroll
        for (int k = 0; k < EPT; k++) {
            int li = k * BT + t;
            if (li < cnt) {
                int i = cb + li;
                int d = dst[i];
                myP[k] = enc_sw(src[i], ew[i]);
                myD[k] = d & 255;
                int b = d >> 8;
                myBin[k] = b;
                myRank[k] = atomicAdd(&h[b], 1);
            } else myBin[k] = -1;
        }
        __syncthreads();
        for (int i = t; i < BINS_MAX; i += BT) sc[i] = (i < nbins) ? h[i] : 0;
        __syncthreads();
        int* cur = sc; int* nxt = sc2;
        for (int off = 1; off < BINS_MAX; off <<= 1) {
            for (int i = t; i < BINS_MAX; i += BT) nxt[i] = cur[i] + (i >= off ? cur[i - off] : 0);
            __syncthreads();
            int* tm = cur; cur = nxt; nxt = tm;
        }
#pragma unroll
        for (int k = 0; k < EPT; k++) {
            int b = myBin[k];
            if (b >= 0) {
                int pos = (b ? cur[b - 1] : 0) + myRank[k];
                sP[pos] = myP[k];
                sD[pos] = (unsigned char)myD[k];
                sB[pos] = (unsigned short)b;
            }
        }
        __syncthreads();
        for (int i = t; i < cnt; i += BT) {
            int b = sB[i];
            int excl = (b ? cur[b - 1] : 0);
            int g = blkOff[b] + cursor[b] + (i - excl);
            sortedP[g] = sP[i];
            sortedDlo[g] = sD[i];
        }
        __syncthreads();
        for (int i = t; i < nbins; i += BT) cursor[i] += h[i];
        __syncthreads();
    }
}

// ---------------- phase D: per-bin counting sort -> padded CSR + node stats ----------------
// Rows padded to multiple of 4 slots (zero edges) and 16B-aligned bases so gather
// kernels can load uint4. Also computes weighted degree, dinv, x~0 = dinv*xin (fp16).
__global__ __launch_bounds__(BT) void k_bin_sort(
    const unsigned* __restrict__ sortedP, const unsigned char* __restrict__ sortedDlo,
    const int* __restrict__ binBase, const float* __restrict__ xin,
    unsigned* __restrict__ pairs, int* __restrict__ rowbeg, int* __restrict__ rowcnt,
    float* __restrict__ dinv, __half2* __restrict__ x0h, int N) {
    __shared__ int cnt[256], a[256], b_[256], cursor[256];
    __shared__ float degs[256];
    int bin = blockIdx.x, t = threadIdx.x;  // BT == 256
    int e0 = binBase[bin], e1 = binBase[bin + 1];
    int e0p = ((e0 + 3) & ~3) + bin * BIN_PAD;  // aligned padded base for this bin
    int nodeBase = bin << 8;
    int nn = min(256, N - nodeBase);
    cnt[t] = 0;
    degs[t] = 0.0f;
    __syncthreads();
    for (int i = e0 + t; i < e1; i += BT) atomicAdd(&cnt[sortedDlo[i]], 1);
    __syncthreads();
    int realc = cnt[t];
    int pc = (realc + 3) & ~3;  // padded count (multiple of 4)
    a[t] = pc;
    __syncthreads();
    int* cur = a; int* nxt = b_;
    for (int off = 1; off < 256; off <<= 1) {
        nxt[t] = cur[t] + (t >= off ? cur[t - off] : 0);
        __syncthreads();
        int* tm = cur; cur = nxt; nxt = tm;
    }
    int ex = (t ? cur[t - 1] : 0);  // exclusive padded offset
    if (t < nn) {
        rowbeg[nodeBase + t] = e0p + ex;
        rowcnt[nodeBase + t] = pc;
    }
    __syncthreads();
    cnt[t] = ex;   // repurpose: per-node exclusive padded offset
    cursor[t] = 0;
    __syncthreads();
    for (int i = e0 + t; i < e1; i += BT) {
        int dl = sortedDlo[i];
        unsigned v = sortedP[i];
        atomicAdd(&degs[dl], dec_w(v));
        int r = atomicAdd(&cursor[dl], 1);
        pairs[e0p + cnt[dl] + r] = v;
    }
    __syncthreads();
    // zero-fill pad slots of my node
    for (int z = realc; z < pc; z++) pairs[e0p + ex + z] = 0u;
    if (t < nn) {
        int node = nodeBase + t;
        float d = 1.0f + degs[t];
        float di = rsqrtf(d);
        dinv[node] = di;
        float4 xv = *reinterpret_cast<const float4*>(xin + (size_t)node * 4);
        x0h[(size_t)node * 2 + 0] = __floats2half2_rn(xv.x * di, xv.y * di);
        x0h[(size_t)node * 2 + 1] = __floats2half2_rn(xv.z * di, xv.w * di);
    }
}

// ---------------- fused layer (layers 1,2): lane-split output columns ----------------
template <int FIN, int FOUT, int TPN, int SPLIT>
__global__ void k_layer(const int* __restrict__ rowbeg, const int* __restrict__ rowcnt,
                        const unsigned* __restrict__ pairs,
                        const __half2* __restrict__ x, const float* __restrict__ dinv,
                        const float* __restrict__ W, const float* __restrict__ b,
                        __half* __restrict__ outA, __half* __restrict__ outB, int N) {
    constexpr int H = FIN / 2;
    constexpr int P = FOUT + 1;
    constexpr int KX = (H + TPN - 1) / TPN;
    constexpr int CPL = FOUT / TPN;  // columns per lane
    __shared__ float Ws[FIN * P];
    __shared__ float bs[FOUT];
    for (int t = threadIdx.x; t < FIN * FOUT; t += blockDim.x) {
        int r = t / FOUT, c = t - r * FOUT;
        Ws[r * P + c] = W[t];
    }
    for (int t = threadIdx.x; t < FOUT; t += blockDim.x) bs[t] = b[t];
    __syncthreads();
    int gid = blockIdx.x * blockDim.x + threadIdx.x;
    int node = gid / TPN;
    int l = gid & (TPN - 1);
    if (node >= N) return;
    int beg = rowbeg[node], pc = rowcnt[node];

    float2 acc[KX];
#pragma unroll
    for (int k = 0; k < KX; k++) acc[k] = make_float2(0.0f, 0.0f);

    for (int e = beg; e < beg + pc; e += 4) {
        uint4 q = *reinterpret_cast<const uint4*>(pairs + e);  // 16B-aligned
        const __half2* r0 = x + (size_t)dec_s(q.x) * H;
        const __half2* r1 = x + (size_t)dec_s(q.y) * H;
        const __half2* r2 = x + (size_t)dec_s(q.z) * H;
        const __half2* r3 = x + (size_t)dec_s(q.w) * H;
        float w0 = dec_w(q.x), w1 = dec_w(q.y), w2 = dec_w(q.z), w3 = dec_w(q.w);
#pragma unroll
        for (int k = 0; k < KX; k++) {
            int m = l + TPN * k;
            if (m < H) {
                float2 v0 = __half22float2(r0[m]);
                float2 v1 = __half22float2(r1[m]);
                float2 v2 = __half22float2(r2[m]);
                float2 v3 = __half22float2(r3[m]);
                acc[k].x += v0.x * w0 + v1.x * w1 + v2.x * w2 + v3.x * w3;
                acc[k].y += v0.y * w0 + v1.y * w1 + v2.y * w2 + v3.y * w3;
            }
        }
    }
    {   // self-loop (weight 1)
        const __half2* rn = x + (size_t)node * H;
#pragma unroll
        for (int k = 0; k < KX; k++) {
            int m = l + TPN * k;
            if (m < H) {
                float2 v = __half22float2(rn[m]);
                acc[k].x += v.x;
                acc[k].y += v.y;
            }
        }
    }
    float dv = dinv[node];
    float p[CPL];
#pragma unroll
    for (int q = 0; q < CPL; q++) p[q] = 0.0f;
#pragma unroll
    for (int m = 0; m < H; m++) {  // broadcast owned pairs to the group
        float ax = __shfl(acc[m / TPN].x, m % TPN, TPN);
        float ay = __shfl(acc[m / TPN].y, m % TPN, TPN);
        const float* w0r = Ws + (2 * m) * P;
        const float* w1r = Ws + (2 * m + 1) * P;
#pragma unroll
        for (int q = 0; q < CPL; q++) {
            int j = l + TPN * q;
            p[q] += ax * w0r[j] + ay * w1r[j];
        }
    }
#pragma unroll
    for (int q = 0; q < CPL; q++) {
        int j = l + TPN * q;
        float a = leaky(dv * p[q] + bs[j]) * dv;
        __half hv = __float2half_rn(a);
        if (j < SPLIT) outA[(size_t)node * SPLIT + j] = hv;
        else outB[(size_t)node * (FOUT - SPLIT) + (j - SPLIT)] = hv;
    }
}

// ---------------- layer-3 gather pass: y = agg(x~half) + self, fp32 [N][6] float2 ----------------
__global__ void k_agg(const int* __restrict__ rowbeg, const int* __restrict__ rowcnt,
                      const unsigned* __restrict__ pairs,
                      const __half2* __restrict__ xa, float2* __restrict__ y2, int N) {
    constexpr int H = 6;
    int gid = blockIdx.x * blockDim.x + threadIdx.x;
    int node = gid >> 2;
    int l = gid & 3;
    if (node >= N) return;
    int beg = rowbeg[node], pc = rowcnt[node];
    float2 acc[2];
    acc[0] = make_float2(0.0f, 0.0f);
    acc[1] = make_float2(0.0f, 0.0f);
    for (int e = beg; e < beg + pc; e += 4) {
        uint4 q = *reinterpret_cast<const uint4*>(pairs + e);
        const __half2* r0 = xa + (size_t)dec_s(q.x) * H;
        const __half2* r1 = xa + (size_t)dec_s(q.y) * H;
        const __half2* r2 = xa + (size_t)dec_s(q.z) * H;
        const __half2* r3 = xa + (size_t)dec_s(q.w) * H;
        float w0 = dec_w(q.x), w1 = dec_w(q.y), w2 = dec_w(q.z), w3 = dec_w(q.w);
#pragma unroll
        for (int k = 0; k < 2; k++) {
            int m = l + 4 * k;
            if (m < H) {
                float2 v0 = __half22float2(r0[m]);
                float2 v1 = __half22float2(r1[m]);
                float2 v2 = __half22float2(r2[m]);
                float2 v3 = __half22float2(r3[m]);
                acc[k].x += v0.x * w0 + v1.x * w1 + v2.x * w2 + v3.x * w3;
                acc[k].y += v0.y * w0 + v1.y * w1 + v2.y * w2 + v3.y * w3;
            }
        }
    }
    const __half2* rn = xa + (size_t)node * H;
#pragma unroll
    for (int k = 0; k < 2; k++) {
        int m = l + 4 * k;
        if (m < H) {
            float2 v = __half22float2(rn[m]);
            acc[k].x += v.x;
            acc[k].y += v.y;
            y2[(size_t)node * H + m] = acc[k];
        }
    }
}

// ---------------- layer-3 matmul+pool: stream ya/yb, 24x48, leaky, pool ----------------
// TPN=8: lane l owns output cols j=l+8q (q<6); lanes 0-5 own input slot m=l.
__global__ __launch_bounds__(256) void k_mmpool(
    const float2* __restrict__ ya, const float2* __restrict__ yb,
    const float* __restrict__ dinv, const float* __restrict__ W,
    const float* __restrict__ b, float* __restrict__ g, int N) {
    constexpr int FOUT = 48, P = FOUT + 1, CPL = 6;
    __shared__ float Ws[24 * P];
    __shared__ float bs[FOUT];
    __shared__ float pool[FOUT];
    int t = threadIdx.x;
    for (int i = t; i < 24 * FOUT; i += 256) {
        int r = i / FOUT, c = i - r * FOUT;
        Ws[r * P + c] = W[i];
    }
    for (int i = t; i < FOUT; i += 256) {
        bs[i] = b[i];
        pool[i] = 0.0f;
    }
    __syncthreads();
    int l = t & 7;
    float pacc[CPL];
#pragma unroll
    for (int q = 0; q < CPL; q++) pacc[q] = 0.0f;

    int stride = (int)(gridDim.x * blockDim.x);  // multiple of 8
    for (int idx = blockIdx.x * 256 + t; idx < N * 8; idx += stride) {
        int node = idx >> 3;
        float2 va = (l < 6) ? ya[(size_t)node * 6 + l] : make_float2(0.0f, 0.0f);
        float2 vb = (l < 6) ? yb[(size_t)node * 6 + l] : make_float2(0.0f, 0.0f);
        float dv = dinv[node];
        float p[CPL];
#pragma unroll
        for (int q = 0; q < CPL; q++) p[q] = 0.0f;
#pragma unroll
        for (int m = 0; m < 6; m++) {
            float ax = __shfl(va.x, m, 8);
            float ay = __shfl(va.y, m, 8);
            float bx = __shfl(vb.x, m, 8);
            float by = __shfl(vb.y, m, 8);
            const float* wa0 = Ws + (2 * m) * P;
            const float* wa1 = Ws + (2 * m + 1) * P;
            const float* wb0 = Ws + (12 + 2 * m) * P;
            const float* wb1 = Ws + (12 + 2 * m + 1) * P;
#pragma unroll
            for (int q = 0; q < CPL; q++) {
                int j = l + 8 * q;
                p[q] += ax * wa0[j] + ay * wa1[j] + bx * wb0[j] + by * wb1[j];
            }
        }
#pragma unroll
        for (int q = 0; q < CPL; q++) pacc[q] += leaky(dv * p[q] + bs[l + 8 * q]);
    }
#pragma unroll
    for (int q = 0; q < CPL; q++) atomicAdd(&pool[l + 8 * q], pacc[q]);
    __syncthreads();
    if (t < FOUT) atomicAdd(&g[t], pool[t]);
}

// ---------------- FC head: g[48] -> 32 -> 16 -> 2 ----------------
__global__ void k_head(const float* __restrict__ g,
                       const float* __restrict__ fcW1, const float* __restrict__ fcb1,
                       const float* __restrict__ fcW2, const float* __restrict__ fcb2,
                       const float* __restrict__ fcW3, const float* __restrict__ fcb3,
                       float* __restrict__ out) {
    __shared__ float gs[48], t1[32], t2[16];
    int t = threadIdx.x;
    if (t < 48) gs[t] = g[t];
    __syncthreads();
    if (t < 32) {
        float a = fcb1[t];
#pragma unroll
        for (int k = 0; k < 48; k++) a += gs[k] * fcW1[k * 32 + t];
        t1[t] = leaky(a);
    }
    __syncthreads();
    if (t < 16) {
        float a = fcb2[t];
#pragma unroll
        for (int k = 0; k < 32; k++) a += t1[k] * fcW2[k * 16 + t];
        t2[t] = leaky(a);
    }
    __syncthreads();
    if (t < 2) {
        float a = fcb3[t];
#pragma unroll
        for (int k = 0; k < 16; k++) a += t2[k] * fcW3[k * 2 + t];
        out[t] = a;
    }
}

extern "C" void kernel_launch(void* const* d_in, const int* in_sizes, int n_in,
                              void* d_out, int out_size, void* d_ws, size_t ws_size,
                              hipStream_t stream) {
    const float* xin = (const float*)d_in[0];   // [N,4]
    const float* ew  = (const float*)d_in[1];   // [E]
    const int*   ei  = (const int*)d_in[2];     // [2,E]
    const float* W1  = (const float*)d_in[3];
    const float* b1  = (const float*)d_in[4];
    const float* W2  = (const float*)d_in[5];
    const float* b2  = (const float*)d_in[6];
    const float* W3  = (const float*)d_in[7];
    const float* b3  = (const float*)d_in[8];
    const float* fcW1 = (const float*)d_in[9];
    const float* fcb1 = (const float*)d_in[10];
    const float* fcW2 = (const float*)d_in[11];
    const float* fcb2 = (const float*)d_in[12];
    const float* fcW3 = (const float*)d_in[13];
    const float* fcb3 = (const float*)d_in[14];

    const int N = in_sizes[0] / 4;
    const int E = in_sizes[1];
    const int* src = ei;
    const int* dst = ei + E;
    const int nbins = (N + 255) >> 8;      // 391 for N=100k
    const int EPB = cdiv(E, NBLK);

    // workspace layout, 16B-aligned chunks
    char* p_ = (char*)d_ws;
    auto alloc = [&](size_t bytes) { char* r = p_; p_ += (bytes + 15) & ~(size_t)15; return r; };
    unsigned* sortedP = (unsigned*)alloc((size_t)E * 4);
    unsigned* pairs   = (unsigned*)alloc(((size_t)E + (size_t)nbins * BIN_PAD + 16) * 4);
    unsigned char* sortedDlo = (unsigned char*)alloc((size_t)E);
    int*   hist    = (int*)alloc((size_t)BINS_MAX * NBLK * 4);
    int*   binTot  = (int*)alloc((size_t)BINS_MAX * 4);
    int*   binBase = (int*)alloc((size_t)(BINS_MAX + 1) * 4);
    int*   rowbeg  = (int*)alloc((size_t)N * 4);
    int*   rowcnt  = (int*)alloc((size_t)N * 4);
    float* dinv    = (float*)alloc((size_t)N * 4);
    __half2* x0h   = (__half2*)alloc((size_t)N * 2 * 4);   // [N][2]  x~0
    __half*  h1    = (__half*)alloc((size_t)N * 12 * 2);   // [N][12] x~1
    __half*  h2a   = (__half*)alloc((size_t)N * 12 * 2);   // [N][12] x~2 feats 0-11
    __half*  h2b   = (__half*)alloc((size_t)N * 12 * 2);   // [N][12] x~2 feats 12-23
    float2* ya     = (float2*)alloc((size_t)N * 6 * 8);    // [N][6]  l3 agg feats 0-11
    float2* yb     = (float2*)alloc((size_t)N * 6 * 8);    // [N][6]  l3 agg feats 12-23
    float* g       = (float*)alloc(48 * 4);

    // --- sort-based CSR build + node stats (no fabric atomics) ---
    k_hist<<<NBLK, BT, 0, stream>>>(dst, hist, E, EPB, nbins);
    k_scan_cols<<<nbins, BT, 0, stream>>>(hist, binTot);
    k_scan_bins<<<1, BT, 0, stream>>>(binTot, binBase, nbins);
    k_scatter_bins<<<NBLK, BT, 0, stream>>>(src, dst, ew, hist, binBase,
                                            sortedP, sortedDlo, E, EPB, nbins);
    k_bin_sort<<<nbins, BT, 0, stream>>>(sortedP, sortedDlo, binBase, xin,
                                         pairs, rowbeg, rowcnt, dinv, x0h, N);

    // --- layers 1,2 (lane-split matmul), layer-2 output split into h2a/h2b ---
    k_layer<4, 12, 2, 12><<<cdiv((long long)N * 2, 256), 256, 0, stream>>>(
        rowbeg, rowcnt, pairs, x0h, dinv, W1, b1, h1, h1, N);
    k_layer<12, 24, 4, 12><<<cdiv((long long)N * 4, 256), 256, 0, stream>>>(
        rowbeg, rowcnt, pairs, (const __half2*)h1, dinv, W2, b2, h2a, h2b, N);

    // --- layer 3: two lean gather passes + streaming matmul/pool ---
    k_agg<<<cdiv((long long)N * 4, 256), 256, 0, stream>>>(
        rowbeg, rowcnt, pairs, (const __half2*)h2a, ya, N);
    k_agg<<<cdiv((long long)N * 4, 256), 256, 0, stream>>>(
        rowbeg, rowcnt, pairs, (const __half2*)h2b, yb, N);
    hipMemsetAsync(g, 0, 48 * sizeof(float), stream);
    k_mmpool<<<1024, 256, 0, stream>>>(ya, yb, dinv, W3, b3, g, N);

    // --- FC head ---
    k_head<<<1, 64, 0, stream>>>(g, fcW1, fcb1, fcW2, fcb2, fcW3, fcb3, (float*)d_out);
}

// Round 9
// 232.284 us; speedup vs baseline: 1.3243x; 1.0578x over previous
//
#include <hip/hip_runtime.h>
#include <hip/hip_bf16.h>
#include <hip/hip_fp16.h>

static inline int cdiv(long long a, int b) { return (int)((a + b - 1) / b); }

#define LEAK 0.1f
__device__ __forceinline__ float leaky(float v) { return v >= 0.0f ? v : LEAK * v; }

// packed edge: bits[31:15] = src (17b), bits[14:0] = fp16(w) >> 1 ; 0 == zero-pad edge
__device__ __forceinline__ int dec_s(unsigned p) { return (int)(p >> 15); }
__device__ __forceinline__ float dec_w(unsigned p) {
    return __half2float(__ushort_as_half((unsigned short)((p & 0x7FFFu) << 1)));
}
__device__ __forceinline__ unsigned enc_sw(int s, float w) {
    return ((unsigned)s << 15) | ((unsigned)__half_as_ushort(__float2half_rn(w)) >> 1);
}

constexpr int BT = 256;        // threads per block (scan kernels)
constexpr int BT2 = 512;       // threads per block (hist / scatter / bin_sort)
constexpr int NBLK = 512;      // edge-partition blocks (phases A/C)
constexpr int CHUNK = 4096;    // edges staged in LDS per pass (phase C)
constexpr int BINS_MAX = 512;  // >= (N+255)/256 for N=100k (391)
constexpr int BIN_PAD = 1024;  // per-bin slack in pairs[] for row padding

// ---------------- phase A: per-(bin, block) histogram of dst>>8 ----------------
__global__ __launch_bounds__(BT2) void k_hist(const int* __restrict__ dst, int* __restrict__ hist,
                                              int E, int EPB, int nbins) {
    __shared__ int h[BINS_MAX];
    for (int i = threadIdx.x; i < nbins; i += BT2) h[i] = 0;
    __syncthreads();
    int base = blockIdx.x * EPB;
    int end = min(base + EPB, E);
    for (int i = base + threadIdx.x; i < end; i += BT2) atomicAdd(&h[dst[i] >> 8], 1);
    __syncthreads();
    for (int i = threadIdx.x; i < nbins; i += BT2) hist[(size_t)i * NBLK + blockIdx.x] = h[i];
}

// ---------------- phase B1: exclusive scan of each bin's row over blocks ----------------
__global__ __launch_bounds__(BT) void k_scan_cols(int* __restrict__ hist, int* __restrict__ binTot) {
    __shared__ int a[NBLK], b_[NBLK];
    int t = threadIdx.x;
    int* H = hist + (size_t)blockIdx.x * NBLK;
    for (int i = t; i < NBLK; i += BT) a[i] = H[i];
    __syncthreads();
    int* cur = a; int* nxt = b_;
    for (int off = 1; off < NBLK; off <<= 1) {
        for (int i = t; i < NBLK; i += BT) nxt[i] = cur[i] + (i >= off ? cur[i - off] : 0);
        __syncthreads();
        int* tm = cur; cur = nxt; nxt = tm;
    }
    for (int i = t; i < NBLK; i += BT) H[i] = (i ? cur[i - 1] : 0);
    if (t == 0) binTot[blockIdx.x] = cur[NBLK - 1];
}

// ---------------- phase B2: exclusive scan over bins ----------------
__global__ __launch_bounds__(BT) void k_scan_bins(const int* __restrict__ binTot,
                                                  int* __restrict__ binBase, int nbins) {
    __shared__ int a[BINS_MAX], b_[BINS_MAX];
    int t = threadIdx.x;
    for (int i = t; i < BINS_MAX; i += BT) a[i] = (i < nbins) ? binTot[i] : 0;
    __syncthreads();
    int* cur = a; int* nxt = b_;
    for (int off = 1; off < BINS_MAX; off <<= 1) {
        for (int i = t; i < BINS_MAX; i += BT) nxt[i] = cur[i] + (i >= off ? cur[i - off] : 0);
        __syncthreads();
        int* tm = cur; cur = nxt; nxt = tm;
    }
    for (int i = t; i < nbins; i += BT) binBase[i] = (i ? cur[i - 1] : 0);
    if (t == 0) binBase[nbins] = cur[nbins - 1];  // == E
}

// ---------------- phase C: LDS-staged scatter of edges into bin order ----------------
__global__ __launch_bounds__(BT2) void k_scatter_bins(
    const int* __restrict__ src, const int* __restrict__ dst, const float* __restrict__ ew,
    const int* __restrict__ colOff, const int* __restrict__ binBase,
    unsigned* __restrict__ sortedP, unsigned char* __restrict__ sortedDlo,
    int E, int EPB, int nbins) {
    constexpr int EPT = CHUNK / BT2;  // 8 edges per thread per chunk
    __shared__ unsigned sP[CHUNK];        // 16 KB
    __shared__ unsigned char sD[CHUNK];   // 4 KB
    __shared__ unsigned short sB[CHUNK];  // 8 KB
    __shared__ int h[BINS_MAX], sc[BINS_MAX], sc2[BINS_MAX];
    __shared__ int blkOff[BINS_MAX], cursor[BINS_MAX];

    int t = threadIdx.x, blk = blockIdx.x;
    if (t < nbins) {
        blkOff[t] = binBase[t] + colOff[(size_t)t * NBLK + blk];
        cursor[t] = 0;
    }
    int base = blk * EPB;
    int bend = min(base + EPB, E);
    for (int cb = base; cb < bend; cb += CHUNK) {
        int cnt = min(CHUNK, bend - cb);
        if (t < BINS_MAX) h[t] = 0;
        __syncthreads();
        int myBin[EPT], myRank[EPT], myD[EPT];
        unsigned myP[EPT];
#pragma unroll
        for (int k = 0; k < EPT; k++) {
            int li = k * BT2 + t;
            if (li < cnt) {
                int i = cb + li;
                int d = dst[i];
                myP[k] = enc_sw(src[i], ew[i]);
                myD[k] = d & 255;
                int b = d >> 8;
                myBin[k] = b;
                myRank[k] = atomicAdd(&h[b], 1);
            } else myBin[k] = -1;
        }
        __syncthreads();
        if (t < BINS_MAX) sc[t] = (t < nbins) ? h[t] : 0;
        __syncthreads();
        int* cur = sc; int* nxt = sc2;
        for (int off = 1; off < BINS_MAX; off <<= 1) {
            if (t < BINS_MAX) nxt[t] = cur[t] + (t >= off ? cur[t - off] : 0);
            __syncthreads();
            int* tm = cur; cur = nxt; nxt = tm;
        }
#pragma unroll
        for (int k = 0; k < EPT; k++) {
            int b = myBin[k];
            if (b >= 0) {
                int pos = (b ? cur[b - 1] : 0) + myRank[k];
                sP[pos] = myP[k];
                sD[pos] = (unsigned char)myD[k];
                sB[pos] = (unsigned short)b;
            }
        }
        __syncthreads();
        for (int i = t; i < cnt; i += BT2) {
            int b = sB[i];
            int excl = (b ? cur[b - 1] : 0);
            int g = blkOff[b] + cursor[b] + (i - excl);
            sortedP[g] = sP[i];
            sortedDlo[g] = sD[i];
        }
        __syncthreads();
        if (t < nbins) cursor[t] += h[t];
        __syncthreads();
    }
}

// ---------------- phase D: per-bin counting sort -> padded CSR + node stats ----------------
// Rows padded to multiple of 4 slots (zero edges) and 16B-aligned bases so gather
// kernels can load uint4. Also computes weighted degree, dinv, x~0 = dinv*xin (fp16).
__global__ __launch_bounds__(BT2) void k_bin_sort(
    const unsigned* __restrict__ sortedP, const unsigned char* __restrict__ sortedDlo,
    const int* __restrict__ binBase, const float* __restrict__ xin,
    unsigned* __restrict__ pairs, int* __restrict__ rowbeg, int* __restrict__ rowcnt,
    float* __restrict__ dinv, __half2* __restrict__ x0h, int N) {
    __shared__ int cnt[256], a[256], b_[256], cursor[256];
    __shared__ float degs[256];
    int bin = blockIdx.x, t = threadIdx.x;
    int e0 = binBase[bin], e1 = binBase[bin + 1];
    int e0p = ((e0 + 3) & ~3) + bin * BIN_PAD;  // aligned padded base for this bin
    int nodeBase = bin << 8;
    int nn = min(256, N - nodeBase);
    if (t < 256) {
        cnt[t] = 0;
        degs[t] = 0.0f;
    }
    __syncthreads();
    for (int i = e0 + t; i < e1; i += BT2) atomicAdd(&cnt[sortedDlo[i]], 1);
    __syncthreads();
    int realc = 0, pc = 0;
    if (t < 256) {
        realc = cnt[t];
        pc = (realc + 3) & ~3;  // padded count (multiple of 4)
        a[t] = pc;
    }
    __syncthreads();
    int* cur = a; int* nxt = b_;
    for (int off = 1; off < 256; off <<= 1) {
        if (t < 256) nxt[t] = cur[t] + (t >= off ? cur[t - off] : 0);
        __syncthreads();
        int* tm = cur; cur = nxt; nxt = tm;
    }
    int ex = 0;
    if (t < 256) {
        ex = (t ? cur[t - 1] : 0);  // exclusive padded offset
        if (t < nn) {
            rowbeg[nodeBase + t] = e0p + ex;
            rowcnt[nodeBase + t] = pc;
        }
    }
    __syncthreads();
    if (t < 256) {
        cnt[t] = ex;   // repurpose: per-node exclusive padded offset
        cursor[t] = 0;
    }
    __syncthreads();
    for (int i = e0 + t; i < e1; i += BT2) {
        int dl = sortedDlo[i];
        unsigned v = sortedP[i];
        atomicAdd(&degs[dl], dec_w(v));
        int r = atomicAdd(&cursor[dl], 1);
        pairs[e0p + cnt[dl] + r] = v;
    }
    __syncthreads();
    if (t < 256) {
        // zero-fill pad slots of my node
        for (int z = realc; z < pc; z++) pairs[e0p + ex + z] = 0u;
        if (t < nn) {
            int node = nodeBase + t;
            float d = 1.0f + degs[t];
            float di = rsqrtf(d);
            dinv[node] = di;
            float4 xv = *reinterpret_cast<const float4*>(xin + (size_t)node * 4);
            x0h[(size_t)node * 2 + 0] = __floats2half2_rn(xv.x * di, xv.y * di);
            x0h[(size_t)node * 2 + 1] = __floats2half2_rn(xv.z * di, xv.w * di);
        }
    }
}

// ---------------- fused layer (layers 1,2): lane-split output columns ----------------
template <int FIN, int FOUT, int TPN, int SPLIT>
__global__ void k_layer(const int* __restrict__ rowbeg, const int* __restrict__ rowcnt,
                        const unsigned* __restrict__ pairs,
                        const __half2* __restrict__ x, const float* __restrict__ dinv,
                        const float* __restrict__ W, const float* __restrict__ b,
                        __half* __restrict__ outA, __half* __restrict__ outB, int N) {
    constexpr int H = FIN / 2;
    constexpr int P = FOUT + 1;
    constexpr int KX = (H + TPN - 1) / TPN;
    constexpr int CPL = FOUT / TPN;  // columns per lane
    __shared__ float Ws[FIN * P];
    __shared__ float bs[FOUT];
    for (int t = threadIdx.x; t < FIN * FOUT; t += blockDim.x) {
        int r = t / FOUT, c = t - r * FOUT;
        Ws[r * P + c] = W[t];
    }
    for (int t = threadIdx.x; t < FOUT; t += blockDim.x) bs[t] = b[t];
    __syncthreads();
    int gid = blockIdx.x * blockDim.x + threadIdx.x;
    int node = gid / TPN;
    int l = gid & (TPN - 1);
    if (node >= N) return;
    int beg = rowbeg[node], pc = rowcnt[node];

    float2 acc[KX];
#pragma unroll
    for (int k = 0; k < KX; k++) acc[k] = make_float2(0.0f, 0.0f);

    for (int e = beg; e < beg + pc; e += 4) {
        uint4 q = *reinterpret_cast<const uint4*>(pairs + e);  // 16B-aligned
        const __half2* r0 = x + (size_t)dec_s(q.x) * H;
        const __half2* r1 = x + (size_t)dec_s(q.y) * H;
        const __half2* r2 = x + (size_t)dec_s(q.z) * H;
        const __half2* r3 = x + (size_t)dec_s(q.w) * H;
        float w0 = dec_w(q.x), w1 = dec_w(q.y), w2 = dec_w(q.z), w3 = dec_w(q.w);
#pragma unroll
        for (int k = 0; k < KX; k++) {
            int m = l + TPN * k;
            if (m < H) {
                float2 v0 = __half22float2(r0[m]);
                float2 v1 = __half22float2(r1[m]);
                float2 v2 = __half22float2(r2[m]);
                float2 v3 = __half22float2(r3[m]);
                acc[k].x += v0.x * w0 + v1.x * w1 + v2.x * w2 + v3.x * w3;
                acc[k].y += v0.y * w0 + v1.y * w1 + v2.y * w2 + v3.y * w3;
            }
        }
    }
    {   // self-loop (weight 1)
        const __half2* rn = x + (size_t)node * H;
#pragma unroll
        for (int k = 0; k < KX; k++) {
            int m = l + TPN * k;
            if (m < H) {
                float2 v = __half22float2(rn[m]);
                acc[k].x += v.x;
                acc[k].y += v.y;
            }
        }
    }
    float dv = dinv[node];
    float p[CPL];
#pragma unroll
    for (int q = 0; q < CPL; q++) p[q] = 0.0f;
#pragma unroll
    for (int m = 0; m < H; m++) {  // broadcast owned pairs to the group
        float ax = __shfl(acc[m / TPN].x, m % TPN, TPN);
        float ay = __shfl(acc[m / TPN].y, m % TPN, TPN);
        const float* w0r = Ws + (2 * m) * P;
        const float* w1r = Ws + (2 * m + 1) * P;
#pragma unroll
        for (int q = 0; q < CPL; q++) {
            int j = l + TPN * q;
            p[q] += ax * w0r[j] + ay * w1r[j];
        }
    }
#pragma unroll
    for (int q = 0; q < CPL; q++) {
        int j = l + TPN * q;
        float a = leaky(dv * p[q] + bs[j]) * dv;
        __half hv = __float2half_rn(a);
        if (j < SPLIT) outA[(size_t)node * SPLIT + j] = hv;
        else outB[(size_t)node * (FOUT - SPLIT) + (j - SPLIT)] = hv;
    }
}

// ---------------- layer-3 gather pass: y = agg(x~half) + self, fp32 [N][6] float2 ----------------
__global__ void k_agg(const int* __restrict__ rowbeg, const int* __restrict__ rowcnt,
                      const unsigned* __restrict__ pairs,
                      const __half2* __restrict__ xa, float2* __restrict__ y2, int N) {
    constexpr int H = 6;
    int gid = blockIdx.x * blockDim.x + threadIdx.x;
    int node = gid >> 2;
    int l = gid & 3;
    if (node >= N) return;
    int beg = rowbeg[node], pc = rowcnt[node];
    float2 acc[2];
    acc[0] = make_float2(0.0f, 0.0f);
    acc[1] = make_float2(0.0f, 0.0f);
    for (int e = beg; e < beg + pc; e += 4) {
        uint4 q = *reinterpret_cast<const uint4*>(pairs + e);
        const __half2* r0 = xa + (size_t)dec_s(q.x) * H;
        const __half2* r1 = xa + (size_t)dec_s(q.y) * H;
        const __half2* r2 = xa + (size_t)dec_s(q.z) * H;
        const __half2* r3 = xa + (size_t)dec_s(q.w) * H;
        float w0 = dec_w(q.x), w1 = dec_w(q.y), w2 = dec_w(q.z), w3 = dec_w(q.w);
#pragma unroll
        for (int k = 0; k < 2; k++) {
            int m = l + 4 * k;
            if (m < H) {
                float2 v0 = __half22float2(r0[m]);
                float2 v1 = __half22float2(r1[m]);
                float2 v2 = __half22float2(r2[m]);
                float2 v3 = __half22float2(r3[m]);
                acc[k].x += v0.x * w0 + v1.x * w1 + v2.x * w2 + v3.x * w3;
                acc[k].y += v0.y * w0 + v1.y * w1 + v2.y * w2 + v3.y * w3;
            }
        }
    }
    const __half2* rn = xa + (size_t)node * H;
#pragma unroll
    for (int k = 0; k < 2; k++) {
        int m = l + 4 * k;
        if (m < H) {
            float2 v = __half22float2(rn[m]);
            acc[k].x += v.x;
            acc[k].y += v.y;
            y2[(size_t)node * H + m] = acc[k];
        }
    }
}

// ---------------- layer-3 matmul+pool: stream ya/yb, 24x48, leaky, pool ----------------
// TPN=8: lane l owns output cols j=l+8q (q<6); lanes 0-5 own input slot m=l.
__global__ __launch_bounds__(256) void k_mmpool(
    const float2* __restrict__ ya, const float2* __restrict__ yb,
    const float* __restrict__ dinv, const float* __restrict__ W,
    const float* __restrict__ b, float* __restrict__ g, int N) {
    constexpr int FOUT = 48, P = FOUT + 1, CPL = 6;
    __shared__ float Ws[24 * P];
    __shared__ float bs[FOUT];
    __shared__ float pool[FOUT];
    int t = threadIdx.x;
    for (int i = t; i < 24 * FOUT; i += 256) {
        int r = i / FOUT, c = i - r * FOUT;
        Ws[r * P + c] = W[i];
    }
    for (int i = t; i < FOUT; i += 256) {
        bs[i] = b[i];
        pool[i] = 0.0f;
    }
    __syncthreads();
    int l = t & 7;
    float pacc[CPL];
#pragma unroll
    for (int q = 0; q < CPL; q++) pacc[q] = 0.0f;

    int stride = (int)(gridDim.x * blockDim.x);  // multiple of 8
    for (int idx = blockIdx.x * 256 + t; idx < N * 8; idx += stride) {
        int node = idx >> 3;
        float2 va = (l < 6) ? ya[(size_t)node * 6 + l] : make_float2(0.0f, 0.0f);
        float2 vb = (l < 6) ? yb[(size_t)node * 6 + l] : make_float2(0.0f, 0.0f);
        float dv = dinv[node];
        float p[CPL];
#pragma unroll
        for (int q = 0; q < CPL; q++) p[q] = 0.0f;
#pragma unroll
        for (int m = 0; m < 6; m++) {
            float ax = __shfl(va.x, m, 8);
            float ay = __shfl(va.y, m, 8);
            float bx = __shfl(vb.x, m, 8);
            float by = __shfl(vb.y, m, 8);
            const float* wa0 = Ws + (2 * m) * P;
            const float* wa1 = Ws + (2 * m + 1) * P;
            const float* wb0 = Ws + (12 + 2 * m) * P;
            const float* wb1 = Ws + (12 + 2 * m + 1) * P;
#pragma unroll
            for (int q = 0; q < CPL; q++) {
                int j = l + 8 * q;
                p[q] += ax * wa0[j] + ay * wa1[j] + bx * wb0[j] + by * wb1[j];
            }
        }
#pragma unroll
        for (int q = 0; q < CPL; q++) pacc[q] += leaky(dv * p[q] + bs[l + 8 * q]);
    }
#pragma unroll
    for (int q = 0; q < CPL; q++) atomicAdd(&pool[l + 8 * q], pacc[q]);
    __syncthreads();
    if (t < FOUT) atomicAdd(&g[t], pool[t]);
}

// ---------------- FC head: g[48] -> 32 -> 16 -> 2 ----------------
__global__ void k_head(const float* __restrict__ g,
                       const float* __restrict__ fcW1, const float* __restrict__ fcb1,
                       const float* __restrict__ fcW2, const float* __restrict__ fcb2,
                       const float* __restrict__ fcW3, const float* __restrict__ fcb3,
                       float* __restrict__ out) {
    __shared__ float gs[48], t1[32], t2[16];
    int t = threadIdx.x;
    if (t < 48) gs[t] = g[t];
    __syncthreads();
    if (t < 32) {
        float a = fcb1[t];
#pragma unroll
        for (int k = 0; k < 48; k++) a += gs[k] * fcW1[k * 32 + t];
        t1[t] = leaky(a);
    }
    __syncthreads();
    if (t < 16) {
        float a = fcb2[t];
#pragma unroll
        for (int k = 0; k < 32; k++) a += t1[k] * fcW2[k * 16 + t];
        t2[t] = leaky(a);
    }
    __syncthreads();
    if (t < 2) {
        float a = fcb3[t];
#pragma unroll
        for (int k = 0; k < 16; k++) a += t2[k] * fcW3[k * 2 + t];
        out[t] = a;
    }
}

extern "C" void kernel_launch(void* const* d_in, const int* in_sizes, int n_in,
                              void* d_out, int out_size, void* d_ws, size_t ws_size,
                              hipStream_t stream) {
    const float* xin = (const float*)d_in[0];   // [N,4]
    const float* ew  = (const float*)d_in[1];   // [E]
    const int*   ei  = (const int*)d_in[2];     // [2,E]
    const float* W1  = (const float*)d_in[3];
    const float* b1  = (const float*)d_in[4];
    const float* W2  = (const float*)d_in[5];
    const float* b2  = (const float*)d_in[6];
    const float* W3  = (const float*)d_in[7];
    const float* b3  = (const float*)d_in[8];
    const float* fcW1 = (const float*)d_in[9];
    const float* fcb1 = (const float*)d_in[10];
    const float* fcW2 = (const float*)d_in[11];
    const float* fcb2 = (const float*)d_in[12];
    const float* fcW3 = (const float*)d_in[13];
    const float* fcb3 = (const float*)d_in[14];

    const int N = in_sizes[0] / 4;
    const int E = in_sizes[1];
    const int* src = ei;
    const int* dst = ei + E;
    const int nbins = (N + 255) >> 8;      // 391 for N=100k
    const int EPB = cdiv(E, NBLK);

    // workspace layout, 16B-aligned chunks
    char* p_ = (char*)d_ws;
    auto alloc = [&](size_t bytes) { char* r = p_; p_ += (bytes + 15) & ~(size_t)15; return r; };
    unsigned* sortedP = (unsigned*)alloc((size_t)E * 4);
    unsigned* pairs   = (unsigned*)alloc(((size_t)E + (size_t)nbins * BIN_PAD + 16) * 4);
    unsigned char* sortedDlo = (unsigned char*)alloc((size_t)E);
    int*   hist    = (int*)alloc((size_t)BINS_MAX * NBLK * 4);
    int*   binTot  = (int*)alloc((size_t)BINS_MAX * 4);
    int*   binBase = (int*)alloc((size_t)(BINS_MAX + 1) * 4);
    int*   rowbeg  = (int*)alloc((size_t)N * 4);
    int*   rowcnt  = (int*)alloc((size_t)N * 4);
    float* dinv    = (float*)alloc((size_t)N * 4);
    __half2* x0h   = (__half2*)alloc((size_t)N * 2 * 4);   // [N][2]  x~0
    __half*  h1    = (__half*)alloc((size_t)N * 12 * 2);   // [N][12] x~1
    __half*  h2a   = (__half*)alloc((size_t)N * 12 * 2);   // [N][12] x~2 feats 0-11
    __half*  h2b   = (__half*)alloc((size_t)N * 12 * 2);   // [N][12] x~2 feats 12-23
    float2* ya     = (float2*)alloc((size_t)N * 6 * 8);    // [N][6]  l3 agg feats 0-11
    float2* yb     = (float2*)alloc((size_t)N * 6 * 8);    // [N][6]  l3 agg feats 12-23
    float* g       = (float*)alloc(48 * 4);

    // --- sort-based CSR build + node stats (no fabric atomics) ---
    k_hist<<<NBLK, BT2, 0, stream>>>(dst, hist, E, EPB, nbins);
    k_scan_cols<<<nbins, BT, 0, stream>>>(hist, binTot);
    k_scan_bins<<<1, BT, 0, stream>>>(binTot, binBase, nbins);
    k_scatter_bins<<<NBLK, BT2, 0, stream>>>(src, dst, ew, hist, binBase,
                                             sortedP, sortedDlo, E, EPB, nbins);
    k_bin_sort<<<nbins, BT2, 0, stream>>>(sortedP, sortedDlo, binBase, xin,
                                          pairs, rowbeg, rowcnt, dinv, x0h, N);

    // --- layers 1,2 (lane-split matmul), layer-2 output split into h2a/h2b ---
    k_layer<4, 12, 2, 12><<<cdiv((long long)N * 2, 256), 256, 0, stream>>>(
        rowbeg, rowcnt, pairs, x0h, dinv, W1, b1, h1, h1, N);
    k_layer<12, 24, 4, 12><<<cdiv((long long)N * 4, 256), 256, 0, stream>>>(
        rowbeg, rowcnt, pairs, (const __half2*)h1, dinv, W2, b2, h2a, h2b, N);

    // --- layer 3: two lean gather passes + streaming matmul/pool ---
    k_agg<<<cdiv((long long)N * 4, 256), 256, 0, stream>>>(
        rowbeg, rowcnt, pairs, (const __half2*)h2a, ya, N);
    k_agg<<<cdiv((long long)N * 4, 256), 256, 0, stream>>>(
        rowbeg, rowcnt, pairs, (const __half2*)h2b, yb, N);
    hipMemsetAsync(g, 0, 48 * sizeof(float), stream);
    k_mmpool<<<1024, 256, 0, stream>>>(ya, yb, dinv, W3, b3, g, N);

    // --- FC head ---
    k_head<<<1, 64, 0, stream>>>(g, fcW1, fcb1, fcW2, fcb2, fcW3, fcb3, (float*)d_out);
}